// Round 1
// 522.720 us; speedup vs baseline: 1.1257x; 1.1257x over previous
//
#include <hip/hip_runtime.h>
#include <math.h>

#define L_TOK 257
#define N_B 32
#define C_DIM 768
#define N_H 12
#define HD 64
#define BH (N_B * N_H)          /* 384 */
#define M_TOK (L_TOK * N_B)     /* 8224 */
#define HW 256
#define RPE_NUM 33
#define LOGIT_MAX 4.6051701859880913680f
#define VT_STRIDE 264           /* 257 padded to mult of 8 -> 16B-aligned short8 rows */

typedef unsigned short ushort;
typedef unsigned int uint;
typedef __attribute__((ext_vector_type(8))) short short8;
typedef __attribute__((ext_vector_type(4))) float f32x4;

__device__ __forceinline__ ushort f2bf_rn(float f) {
  uint u = __float_as_uint(f);
  uint r = (u + 0x7FFF + ((u >> 16) & 1)) >> 16;
  return (ushort)r;
}
__device__ __forceinline__ float bf2f(ushort h) {
  return __uint_as_float(((uint)h) << 16);
}

// ---------------- fp32 -> bf16 hi/lo split ----------------
__global__ __launch_bounds__(256)
void cvt_split(const float* __restrict__ src, ushort* __restrict__ hi,
               ushort* __restrict__ lo, int n) {
  int i = (blockIdx.x * 256 + threadIdx.x) * 4;
  if (i + 3 >= n + 3) return;
  if (i + 3 < n) {
    float4 v = *(const float4*)(src + i);
    ushort h0 = f2bf_rn(v.x), h1 = f2bf_rn(v.y), h2 = f2bf_rn(v.z), h3 = f2bf_rn(v.w);
    ushort l0 = f2bf_rn(v.x - bf2f(h0)), l1 = f2bf_rn(v.y - bf2f(h1));
    ushort l2 = f2bf_rn(v.z - bf2f(h2)), l3 = f2bf_rn(v.w - bf2f(h3));
    *(ushort4*)(hi + i) = make_ushort4(h0, h1, h2, h3);
    *(ushort4*)(lo + i) = make_ushort4(l0, l1, l2, l3);
  } else {
    for (int k = i; k < n; ++k) {
      float vv = src[k];
      ushort h = f2bf_rn(vv);
      hi[k] = h; lo[k] = f2bf_rn(vv - bf2f(h));
    }
  }
}

// ---------------- split-bf16 MFMA GEMM: C[M][Nn] = A[M][K] @ W[Nn][K]^T + bias ----------------
__global__ __launch_bounds__(256)
void gemm_mfma_split(const ushort* __restrict__ Ahi, const ushort* __restrict__ Alo,
                     const ushort* __restrict__ Bhi, const ushort* __restrict__ Blo,
                     const float* __restrict__ bias, float* __restrict__ Cout,
                     int M, int Nn, int K) {
  __shared__ __align__(16) ushort lds[4 * 128 * 32];   // 32 KB
  ushort* sAh = lds;
  ushort* sAl = lds + 4096;
  ushort* sBh = lds + 8192;
  ushort* sBl = lds + 12288;

  const int t = threadIdx.x;
  const int wave = t >> 6, lane = t & 63;
  const int wm = (wave & 1) * 64;
  const int wn = (wave >> 1) * 64;
  const int m0 = blockIdx.x * 128;
  const int n0 = blockIdx.y * 128;

  const int ar = t >> 2;
  const int ac = (t & 3) * 8;
  const uint ldsOff = (uint)(t & 192) * 16;

  const int frm = lane & 15;
  const int frk = (lane >> 4) * 8;

  f32x4 acc[4][4] = {};

  for (int k0 = 0; k0 < K; k0 += 32) {
#pragma unroll
    for (int half = 0; half < 2; ++half) {
      int rA = m0 + half * 64 + ar; if (rA > M - 1) rA = M - 1;
      int rB = n0 + half * 64 + ar;
      size_t gA = (size_t)rA * K + k0 + ac;
      size_t gB = (size_t)rB * K + k0 + ac;
      uint so = (uint)half * 4096 + ldsOff;
      __builtin_amdgcn_global_load_lds(
          (const __attribute__((address_space(1))) void*)(Ahi + gA),
          (__attribute__((address_space(3))) void*)((char*)sAh + so), 16, 0, 0);
      __builtin_amdgcn_global_load_lds(
          (const __attribute__((address_space(1))) void*)(Alo + gA),
          (__attribute__((address_space(3))) void*)((char*)sAl + so), 16, 0, 0);
      __builtin_amdgcn_global_load_lds(
          (const __attribute__((address_space(1))) void*)(Bhi + gB),
          (__attribute__((address_space(3))) void*)((char*)sBh + so), 16, 0, 0);
      __builtin_amdgcn_global_load_lds(
          (const __attribute__((address_space(1))) void*)(Blo + gB),
          (__attribute__((address_space(3))) void*)((char*)sBl + so), 16, 0, 0);
    }
    __syncthreads();

    short8 ah[4], al[4], bh[4], bl[4];
#pragma unroll
    for (int i = 0; i < 4; ++i) {
      int r = wm + i * 16 + frm;
      ah[i] = *(const short8*)(sAh + r * 32 + frk);
      al[i] = *(const short8*)(sAl + r * 32 + frk);
      int c = wn + i * 16 + frm;
      bh[i] = *(const short8*)(sBh + c * 32 + frk);
      bl[i] = *(const short8*)(sBl + c * 32 + frk);
    }
#pragma unroll
    for (int i = 0; i < 4; ++i)
#pragma unroll
      for (int j = 0; j < 4; ++j) {
        acc[i][j] = __builtin_amdgcn_mfma_f32_16x16x32_bf16(ah[i], bh[j], acc[i][j], 0, 0, 0);
        acc[i][j] = __builtin_amdgcn_mfma_f32_16x16x32_bf16(ah[i], bl[j], acc[i][j], 0, 0, 0);
        acc[i][j] = __builtin_amdgcn_mfma_f32_16x16x32_bf16(al[i], bh[j], acc[i][j], 0, 0, 0);
      }
    __syncthreads();
  }

  const int ecol = lane & 15;
#pragma unroll
  for (int j = 0; j < 4; ++j) {
    int col = n0 + wn + j * 16 + ecol;
    float bv = bias[col];
#pragma unroll
    for (int i = 0; i < 4; ++i) {
      int rbase = m0 + wm + i * 16 + (lane >> 4) * 4;
#pragma unroll
      for (int r = 0; r < 4; ++r) {
        int row = rbase + r;
        if (row < M) Cout[(size_t)row * Nn + col] = acc[i][j][r] + bv;
      }
    }
  }
}

// ---------------- repack qkv -> q/k bf16 hi/lo splits + v fp32, [b][l][64] ----------------
__global__ __launch_bounds__(256)
void repack_norm(const float* __restrict__ qkv,
                 ushort* __restrict__ qhi, ushort* __restrict__ qlo,
                 ushort* __restrict__ khi, ushort* __restrict__ klo,
                 float* __restrict__ v) {
  int gw = blockIdx.x * 4 + (threadIdx.x >> 6);
  int lane = threadIdx.x & 63;
  int b = gw / L_TOK, l = gw - b * L_TOK;
  int n = b / N_H, h = b - n * N_H;
  size_t base = (size_t)(l * N_B + n) * (3 * C_DIM) + h * HD + lane;
  float q = qkv[base];
  float k = qkv[base + C_DIM];
  float vv = qkv[base + 2 * C_DIM];
  float sq = q * q, sk = k * k;
#pragma unroll
  for (int o = 32; o > 0; o >>= 1) {
    sq += __shfl_down(sq, o);
    sk += __shfl_down(sk, o);
  }
  sq = __shfl(sq, 0);
  sk = __shfl(sk, 0);
  float iq = 1.0f / fmaxf(sqrtf(sq), 1e-12f);
  float ik = 1.0f / fmaxf(sqrtf(sk), 1e-12f);
  float qn_ = q * iq, kn_ = k * ik;
  size_t ob = (size_t)(b * L_TOK + l) * HD + lane;
  ushort qh = f2bf_rn(qn_);
  qhi[ob] = qh; qlo[ob] = f2bf_rn(qn_ - bf2f(qh));
  ushort kh = f2bf_rn(kn_);
  khi[ob] = kh; klo[ob] = f2bf_rn(kn_ - bf2f(kh));
  v[ob] = vv;
}

// ---------------- V transpose: v[b][l][64] fp32 -> vt{hi,lo}[b][64][VT_STRIDE] bf16 ----------------
__global__ __launch_bounds__(256)
void vt_make(const float* __restrict__ v, ushort* __restrict__ vthi,
             ushort* __restrict__ vtlo) {
  __shared__ float sT[64][65];
  const int b = blockIdx.x;
  const int t = threadIdx.x;
  const float* vb = v + (size_t)b * L_TOK * HD;
  ushort* vh = vthi + (size_t)b * HD * VT_STRIDE;
  ushort* vl = vtlo + (size_t)b * HD * VT_STRIDE;
  for (int k0 = 0; k0 < 256; k0 += 64) {
#pragma unroll
    for (int p = 0; p < 16; ++p) {
      int idx = p * 256 + t;
      int k = idx >> 6, d = idx & 63;
      sT[d][k] = vb[(size_t)(k0 + k) * HD + d];
    }
    __syncthreads();
#pragma unroll
    for (int p = 0; p < 16; ++p) {
      int idx = p * 256 + t;
      int d = idx >> 6, k = idx & 63;
      float val = sT[d][k];
      ushort h = f2bf_rn(val);
      vh[(size_t)d * VT_STRIDE + k0 + k] = h;
      vl[(size_t)d * VT_STRIDE + k0 + k] = f2bf_rn(val - bf2f(h));
    }
    __syncthreads();
  }
  if (t < HD) {
    float val = vb[(size_t)256 * HD + t];
    ushort h = f2bf_rn(val);
    vh[(size_t)t * VT_STRIDE + 256] = h;
    vl[(size_t)t * VT_STRIDE + 256] = f2bf_rn(val - bf2f(h));
  }
}

// ---------------- MFMA attention: rows 0..255, all 257 cols, softmax -> P ----------------
__global__ __launch_bounds__(256)
void attn_mfma(const ushort* __restrict__ qhi, const ushort* __restrict__ qlo,
               const ushort* __restrict__ khi, const ushort* __restrict__ klo,
               const float* __restrict__ depth, const float* __restrict__ rpe,
               const float* __restrict__ lscale, float* __restrict__ P) {
  __shared__ __align__(16) ushort sKh[256 * 72];   // 36,864 B
  __shared__ __align__(16) ushort sKl[256 * 72];
  __shared__ float cz_s[HW];
  __shared__ float txd[32], tyd[32], tzt[36];
  __shared__ float red_s[16];
  __shared__ float s256[4][16];

  const int tile = blockIdx.x;             // 0..3 -> rows tile*64..tile*64+63
  const int b = blockIdx.y;
  const int n = b / N_H, h = b - n * N_H;
  const int t = threadIdx.x;
  const int lane = t & 63, wave = t >> 6;

  // depth -> cz (bit-exact op sequence vs reference)
  float dval = depth[n * HW + t];
  float mn = dval, mx = dval;
#pragma unroll
  for (int o = 32; o > 0; o >>= 1) {
    mn = fminf(mn, __shfl_down(mn, o));
    mx = fmaxf(mx, __shfl_down(mx, o));
  }
  if (lane == 0) { red_s[wave] = mn; red_s[8 + wave] = mx; }
  __syncthreads();
  float zmin = fminf(fminf(red_s[0], red_s[1]), fminf(red_s[2], red_s[3]));
  float zmax = fmaxf(fmaxf(red_s[8], red_s[9]), fmaxf(red_s[10], red_s[11]));
  float den = zmax - zmin + 1e-8f;
  cz_s[t] = (dval - zmin) / den;
  if (t < 31) {
    int d = t - 15;
    int ix = (int)rintf((float)d * (16.0f / 15.0f));
    ix = max(-16, min(16, ix));
    txd[t] = rpe[(ix + 16) * N_H + h];
    tyd[t] = rpe[(RPE_NUM + ix + 16) * N_H + h];
  }
  if (t < RPE_NUM) tzt[t] = rpe[(2 * RPE_NUM + t) * N_H + h];
  const float scale = expf(fminf(lscale[h], LOGIT_MAX));

  // stage K rows 0..255 (bf16 hi/lo), LDS stride 72 ushorts
  const ushort* khb = khi + (size_t)b * L_TOK * HD;
  const ushort* klb = klo + (size_t)b * L_TOK * HD;
#pragma unroll
  for (int it = 0; it < 8; ++it) {
    int idx = it * 256 + t;
    int j = idx >> 3, c = (idx & 7) * 8;
    *(uint4*)(sKh + j * 72 + c) = *(const uint4*)(khb + (size_t)j * HD + c);
    *(uint4*)(sKl + j * 72 + c) = *(const uint4*)(klb + (size_t)j * HD + c);
  }
  __syncthreads();

  // Q A-frags direct from global (A[m=lane&15][k=(lane>>4)*8+j])
  const int qrow = tile * 64 + 16 * wave;
  const size_t qoff = ((size_t)b * L_TOK + qrow + (lane & 15)) * HD + (lane >> 4) * 8;
  short8 qh0 = *(const short8*)(qhi + qoff);
  short8 qh1 = *(const short8*)(qhi + qoff + 32);
  short8 ql0 = *(const short8*)(qlo + qoff);
  short8 ql1 = *(const short8*)(qlo + qoff + 32);

  f32x4 acc[16] = {};
#pragma unroll
  for (int jt = 0; jt < 16; ++jt) {
    const ushort* bp = sKh + (jt * 16 + (lane & 15)) * 72 + (lane >> 4) * 8;
    const ushort* bq = sKl + (jt * 16 + (lane & 15)) * 72 + (lane >> 4) * 8;
    short8 bh0 = *(const short8*)(bp);
    short8 bh1 = *(const short8*)(bp + 32);
    short8 bl0 = *(const short8*)(bq);
    short8 bl1 = *(const short8*)(bq + 32);
    acc[jt] = __builtin_amdgcn_mfma_f32_16x16x32_bf16(qh0, bh0, acc[jt], 0, 0, 0);
    acc[jt] = __builtin_amdgcn_mfma_f32_16x16x32_bf16(qh1, bh1, acc[jt], 0, 0, 0);
    acc[jt] = __builtin_amdgcn_mfma_f32_16x16x32_bf16(qh0, bl0, acc[jt], 0, 0, 0);
    acc[jt] = __builtin_amdgcn_mfma_f32_16x16x32_bf16(qh1, bl1, acc[jt], 0, 0, 0);
    acc[jt] = __builtin_amdgcn_mfma_f32_16x16x32_bf16(ql0, bh0, acc[jt], 0, 0, 0);
    acc[jt] = __builtin_amdgcn_mfma_f32_16x16x32_bf16(ql1, bh1, acc[jt], 0, 0, 0);
  }

  // col-256 dots via the Q frags (fp32 reconstruct), xor-reduce over k-groups
  {
    const ushort* k6h = khb + (size_t)256 * HD + (lane >> 4) * 8;
    const ushort* k6l = klb + (size_t)256 * HD + (lane >> 4) * 8;
    float p = 0.f;
#pragma unroll
    for (int j = 0; j < 8; ++j) {
      float kf0 = bf2f(k6h[j]) + bf2f(k6l[j]);
      float kf1 = bf2f(k6h[32 + j]) + bf2f(k6l[32 + j]);
      float qf0 = bf2f((ushort)qh0[j]) + bf2f((ushort)ql0[j]);
      float qf1 = bf2f((ushort)qh1[j]) + bf2f((ushort)ql1[j]);
      p = fmaf(qf0, kf0, fmaf(qf1, kf1, p));
    }
    p += __shfl_xor(p, 16);
    p += __shfl_xor(p, 32);
    if (lane < 16) s256[wave][lane] = p;
  }

  const int g = lane >> 4, c0 = lane & 15;

  // col-256 logits (uniform within 16-lane group)
  float lg6[4];
#pragma unroll
  for (int r = 0; r < 4; ++r) {
    int gi = tile * 64 + 16 * wave + 4 * g + r;
    float d6 = s256[wave][4 * g + r];
    float bz = 0.f;
    if (gi >= 1) {
      int dx = ((gi - 1) & 15) - 15;
      int dy = ((gi - 1) >> 4) - 15;
      float rz = (cz_s[gi - 1] - cz_s[255]) * 16.0f;
      int iz = (int)rintf(rz); iz = max(-16, min(16, iz));
      bz = txd[dx + 15] + tyd[dy + 15] + tzt[iz + 16];
    }
    lg6[r] = scale * d6 + bz;
  }

  // bias -> logits in place
#pragma unroll
  for (int jt = 0; jt < 16; ++jt) {
    int col = jt * 16 + c0;
#pragma unroll
    for (int r = 0; r < 4; ++r) {
      int gi = tile * 64 + 16 * wave + 4 * g + r;
      float lv = scale * acc[jt][r];
      if (col >= 1 && gi >= 1) {
        int dx = ((gi - 1) & 15) - ((col - 1) & 15);
        int dy = ((gi - 1) >> 4) - ((col - 1) >> 4);
        float rz = (cz_s[gi - 1] - cz_s[col - 1]) * 16.0f;
        int iz = (int)rintf(rz); iz = max(-16, min(16, iz));
        lv += txd[dx + 15] + tyd[dy + 15] + tzt[iz + 16];
      }
      acc[jt][r] = lv;
    }
  }

  // softmax per row (rows live in (g,r); reduce across low-4 lane bits)
  float* Pb_ = P + (size_t)b * L_TOK * L_TOK;
#pragma unroll
  for (int r = 0; r < 4; ++r) {
    int gi = tile * 64 + 16 * wave + 4 * g + r;
    float m = acc[0][r];
#pragma unroll
    for (int jt = 1; jt < 16; ++jt) m = fmaxf(m, acc[jt][r]);
#pragma unroll
    for (int o = 1; o < 16; o <<= 1) m = fmaxf(m, __shfl_xor(m, o));
    m = fmaxf(m, lg6[r]);
    float s = 0.f;
#pragma unroll
    for (int jt = 0; jt < 16; ++jt) {
      float e = __expf(acc[jt][r] - m);
      acc[jt][r] = e;
      s += e;
    }
#pragma unroll
    for (int o = 1; o < 16; o <<= 1) s += __shfl_xor(s, o);
    float e6 = __expf(lg6[r] - m);
    float inv = 1.0f / (s + e6);
    float* Prow = Pb_ + (size_t)gi * L_TOK;
#pragma unroll
    for (int jt = 0; jt < 16; ++jt)
      Prow[jt * 16 + c0] = acc[jt][r] * inv;
    if (c0 == 0) Prow[256] = e6 * inv;
  }
}

// ---------------- row 256: plain VALU dot + softmax ----------------
__global__ __launch_bounds__(256)
void attn_row256(const ushort* __restrict__ qhi, const ushort* __restrict__ qlo,
                 const ushort* __restrict__ khi, const ushort* __restrict__ klo,
                 const float* __restrict__ depth, const float* __restrict__ rpe,
                 const float* __restrict__ lscale, float* __restrict__ P) {
  __shared__ float qs[HD];
  __shared__ float cz_s[HW];
  __shared__ float txd[32], tyd[32], tzt[36];
  __shared__ float red_s[16];
  __shared__ float lg6_sh;

  const int b = blockIdx.x;
  const int n = b / N_H, h = b - n * N_H;
  const int t = threadIdx.x;
  const int lane = t & 63, wave = t >> 6;

  float dval = depth[n * HW + t];
  float mn = dval, mx = dval;
#pragma unroll
  for (int o = 32; o > 0; o >>= 1) {
    mn = fminf(mn, __shfl_down(mn, o));
    mx = fmaxf(mx, __shfl_down(mx, o));
  }
  if (lane == 0) { red_s[wave] = mn; red_s[8 + wave] = mx; }
  __syncthreads();
  float zmin = fminf(fminf(red_s[0], red_s[1]), fminf(red_s[2], red_s[3]));
  float zmax = fmaxf(fmaxf(red_s[8], red_s[9]), fmaxf(red_s[10], red_s[11]));
  float den = zmax - zmin + 1e-8f;
  cz_s[t] = (dval - zmin) / den;
  if (t < 31) {
    int d = t - 15;
    int ix = (int)rintf((float)d * (16.0f / 15.0f));
    ix = max(-16, min(16, ix));
    txd[t] = rpe[(ix + 16) * N_H + h];
    tyd[t] = rpe[(RPE_NUM + ix + 16) * N_H + h];
  }
  if (t < RPE_NUM) tzt[t] = rpe[(2 * RPE_NUM + t) * N_H + h];
  const float scale = expf(fminf(lscale[h], LOGIT_MAX));

  const size_t q6 = ((size_t)b * L_TOK + 256) * HD;
  if (t < HD) qs[t] = bf2f(qhi[q6 + t]) + bf2f(qlo[q6 + t]);
  __syncthreads();

  // key j = t
  const ushort* krh = khi + ((size_t)b * L_TOK + t) * HD;
  const ushort* krl = klo + ((size_t)b * L_TOK + t) * HD;
  float dot = 0.f;
#pragma unroll
  for (int c = 0; c < HD; c += 8) {
    ushort4 hv0 = *(const ushort4*)(krh + c);
    ushort4 hv1 = *(const ushort4*)(krh + c + 4);
    ushort4 lv0 = *(const ushort4*)(krl + c);
    ushort4 lv1 = *(const ushort4*)(krl + c + 4);
    dot = fmaf(bf2f(hv0.x) + bf2f(lv0.x), qs[c + 0], dot);
    dot = fmaf(bf2f(hv0.y) + bf2f(lv0.y), qs[c + 1], dot);
    dot = fmaf(bf2f(hv0.z) + bf2f(lv0.z), qs[c + 2], dot);
    dot = fmaf(bf2f(hv0.w) + bf2f(lv0.w), qs[c + 3], dot);
    dot = fmaf(bf2f(hv1.x) + bf2f(lv1.x), qs[c + 4], dot);
    dot = fmaf(bf2f(hv1.y) + bf2f(lv1.y), qs[c + 5], dot);
    dot = fmaf(bf2f(hv1.z) + bf2f(lv1.z), qs[c + 6], dot);
    dot = fmaf(bf2f(hv1.w) + bf2f(lv1.w), qs[c + 7], dot);
  }

  float lg;
  {
    float bsum = 0.f;
    if (t >= 1) {
      int dx = 15 - ((t - 1) & 15);
      int dy = 15 - ((t - 1) >> 4);
      float rz = (cz_s[255] - cz_s[t - 1]) * 16.0f;
      int iz = (int)rintf(rz); iz = max(-16, min(16, iz));
      bsum = txd[dx + 15] + tyd[dy + 15] + tzt[iz + 16];
    }
    lg = scale * dot + bsum;
  }

  // key 256 by wave 0
  if (wave == 0) {
    const ushort* k6h = khi + q6;
    const ushort* k6l = klo + q6;
    float pp = (bf2f(k6h[lane]) + bf2f(k6l[lane])) * qs[lane];
#pragma unroll
    for (int o = 32; o > 0; o >>= 1) pp += __shfl_down(pp, o);
    if (lane == 0) {
      // bias(256,256): dx=dy=0, rz=0 -> iz=0
      float bz = txd[15] + tyd[15] + tzt[16];
      lg6_sh = scale * pp + bz;
    }
  }

  // block softmax over 257
  float m = lg;
#pragma unroll
  for (int o = 32; o > 0; o >>= 1) m = fmaxf(m, __shfl_down(m, o));
  if (lane == 0) red_s[wave] = m;
  __syncthreads();
  float M = fmaxf(fmaxf(red_s[0], red_s[1]), fmaxf(red_s[2], red_s[3]));
  M = fmaxf(M, lg6_sh);
  float e = __expf(lg - M);
  float s = e;
#pragma unroll
  for (int o = 32; o > 0; o >>= 1) s += __shfl_down(s, o);
  if (lane == 0) red_s[8 + wave] = s;
  __syncthreads();
  float e6 = __expf(lg6_sh - M);
  float S = (red_s[8] + red_s[9]) + (red_s[10] + red_s[11]) + e6;
  float inv = 1.0f / S;
  float* Prow = P + (size_t)b * L_TOK * L_TOK + (size_t)256 * L_TOK;
  Prow[t] = e * inv;
  if (t == 0) Prow[256] = e6 * inv;
}

// ---------------- PV via MFMA: out(L,N,C) = P(257x257) @ V(257x64) per head-batch ----------------
// A = P rows (fp32 from global -> bf16 hi/lo in regs), B = V^T from vt{hi,lo}.
// 4-product split (hh+hl+lh+ll) keeps PV error ~2^-18 relative. No LDS, no barriers.
__global__ __launch_bounds__(256)
void pv_mfma(const float* __restrict__ P, const ushort* __restrict__ vthi,
             const ushort* __restrict__ vtlo, const float* __restrict__ v,
             float* __restrict__ out_lnc) {
  const int b = blockIdx.y;
  const int n = b / N_H, h = b - n * N_H;
  const int t = threadIdx.x;
  const int lane = t & 63, wave = t >> 6;
  const int rbase = blockIdx.x * 128 + wave * 32;   // 32 rows per wave
  const float* Pb = P + (size_t)b * L_TOK * L_TOK;
  const ushort* vh = vthi + (size_t)b * HD * VT_STRIDE;
  const ushort* vl = vtlo + (size_t)b * HD * VT_STRIDE;

  const int fm = lane & 15, fk = (lane >> 4) * 8;
  f32x4 acc[2][4] = {};

  for (int k0 = 0; k0 < 256; k0 += 32) {
    short8 ah[2], al[2], bh[4], bl[4];
#pragma unroll
    for (int i = 0; i < 2; ++i) {
      const float* pr = Pb + (size_t)(rbase + i * 16 + fm) * L_TOK + k0 + fk;
#pragma unroll
      for (int j = 0; j < 8; ++j) {
        float pv_ = pr[j];
        ushort hh = f2bf_rn(pv_);
        ah[i][j] = (short)hh;
        al[i][j] = (short)f2bf_rn(pv_ - bf2f(hh));
      }
    }
#pragma unroll
    for (int j = 0; j < 4; ++j) {
      const ushort* bp = vh + (size_t)(j * 16 + fm) * VT_STRIDE + k0 + fk;
      const ushort* bq = vl + (size_t)(j * 16 + fm) * VT_STRIDE + k0 + fk;
      bh[j] = *(const short8*)bp;
      bl[j] = *(const short8*)bq;
    }
#pragma unroll
    for (int i = 0; i < 2; ++i)
#pragma unroll
      for (int j = 0; j < 4; ++j) {
        acc[i][j] = __builtin_amdgcn_mfma_f32_16x16x32_bf16(ah[i], bh[j], acc[i][j], 0, 0, 0);
        acc[i][j] = __builtin_amdgcn_mfma_f32_16x16x32_bf16(ah[i], bl[j], acc[i][j], 0, 0, 0);
        acc[i][j] = __builtin_amdgcn_mfma_f32_16x16x32_bf16(al[i], bh[j], acc[i][j], 0, 0, 0);
        acc[i][j] = __builtin_amdgcn_mfma_f32_16x16x32_bf16(al[i], bl[j], acc[i][j], 0, 0, 0);
      }
  }

  // k = 256 tail, exact fp32 (v is [b][l][64])
  const int g = lane >> 4;
  float v6[4];
#pragma unroll
  for (int j = 0; j < 4; ++j)
    v6[j] = v[((size_t)b * L_TOK + 256) * HD + j * 16 + fm];
#pragma unroll
  for (int i = 0; i < 2; ++i)
#pragma unroll
    for (int r = 0; r < 4; ++r) {
      int row = rbase + i * 16 + g * 4 + r;
      float p6 = Pb[(size_t)row * L_TOK + 256];
#pragma unroll
      for (int j = 0; j < 4; ++j) acc[i][j][r] += p6 * v6[j];
    }

  // write out[l][n][C]: C/D layout col = lane&15, row = (lane>>4)*4 + r
#pragma unroll
  for (int i = 0; i < 2; ++i)
#pragma unroll
    for (int r = 0; r < 4; ++r) {
      int row = rbase + i * 16 + g * 4 + r;
      size_t o = ((size_t)row * N_B + n) * C_DIM + h * HD;
#pragma unroll
      for (int j = 0; j < 4; ++j)
        out_lnc[o + j * 16 + fm] = acc[i][j][r];
    }

  // row 256 (exact fp32), done once per b by block.x==0 wave 0
  if (blockIdx.x == 0 && t < HD) {
    const float* Prow = Pb + (size_t)256 * L_TOK;
    const float* vb = v + (size_t)b * L_TOK * HD;
    float sum = 0.f;
    for (int k = 0; k < L_TOK; ++k)
      sum = fmaf(Prow[k], vb[(size_t)k * HD + t], sum);
    out_lnc[((size_t)256 * N_B + n) * C_DIM + h * HD + t] = sum;
  }
}

extern "C" void kernel_launch(void* const* d_in, const int* in_sizes, int n_in,
                              void* d_out, int out_size, void* d_ws, size_t ws_size,
                              hipStream_t stream) {
  const float* x      = (const float*)d_in[0];
  const float* depth  = (const float*)d_in[1];
  const float* w_in   = (const float*)d_in[2];
  const float* b_in   = (const float*)d_in[3];
  const float* w_out  = (const float*)d_in[4];
  const float* b_out  = (const float*)d_in[5];
  const float* rpe    = (const float*)d_in[6];
  const float* lscale = (const float*)d_in[7];
  float* out = (float*)d_out;
  float* ws = (float*)d_ws;

  // layout (float units)
  float* qkv      = ws;                         // 18,948,096 (dead after repack_norm)
  float* attn_lnc = ws;                         // reuse first 6,316,032 (pv output)
  float* v        = ws + 18948096;              // 6,316,032
  ushort* qhi = (ushort*)(ws + 25264128);       // 6,316,032 ushorts each
  ushort* qlo = qhi + 6316032;
  ushort* khi = qlo + 6316032;
  ushort* klo = khi + 6316032;
  ushort* wihi = (ushort*)(ws + 37896192);      // 1,769,472
  ushort* wilo = wihi + 1769472;
  ushort* wohi = wilo + 1769472;                // 589,824
  ushort* wolo = wohi + 589824;
  ushort* xhi = qhi;                            // overlay: dead before repack writes
  ushort* xlo = qlo;
  ushort* ahi = (ushort*)(qkv + 6316032);       // overlay past attn_lnc (post-pv use)
  ushort* alo = ahi + 6316032;
  // vt overlay: float region [6,316,032 .. 12,804,096) — dead between repack_norm
  // (qkv tail) and the post-pv cvt_split (ahi/alo). 384*64*264 = 6,488,064 ushorts each.
  ushort* vthi = (ushort*)(ws + 6316032);
  ushort* vtlo = vthi + 6488064;
  float* Pout = out + 6316032;

  cvt_split<<<6168, 256, 0, stream>>>(x, xhi, xlo, 6316032);
  cvt_split<<<1728, 256, 0, stream>>>(w_in, wihi, wilo, 1769472);
  cvt_split<<<576, 256, 0, stream>>>(w_out, wohi, wolo, 589824);

  gemm_mfma_split<<<dim3(65, 18), 256, 0, stream>>>(xhi, xlo, wihi, wilo, b_in, qkv,
                                                    M_TOK, 3 * C_DIM, C_DIM);
  repack_norm<<<24672, 256, 0, stream>>>(qkv, qhi, qlo, khi, klo, v);
  vt_make<<<BH, 256, 0, stream>>>(v, vthi, vtlo);
  attn_mfma<<<dim3(4, BH), 256, 0, stream>>>(qhi, qlo, khi, klo, depth, rpe, lscale, Pout);
  attn_row256<<<BH, 256, 0, stream>>>(qhi, qlo, khi, klo, depth, rpe, lscale, Pout);
  pv_mfma<<<dim3(2, BH), 256, 0, stream>>>(Pout, vthi, vtlo, v, attn_lnc);

  cvt_split<<<6168, 256, 0, stream>>>(attn_lnc, ahi, alo, 6316032);
  gemm_mfma_split<<<dim3(65, 6), 256, 0, stream>>>(ahi, alo, wohi, wolo, b_out, out,
                                                   M_TOK, C_DIM, C_DIM);
}

// Round 2
// 502.045 us; speedup vs baseline: 1.1721x; 1.0412x over previous
//
#include <hip/hip_runtime.h>
#include <math.h>

#define L_TOK 257
#define N_B 32
#define C_DIM 768
#define N_H 12
#define HD 64
#define BH (N_B * N_H)          /* 384 */
#define M_TOK (L_TOK * N_B)     /* 8224 */
#define HW 256
#define RPE_NUM 33
#define LOGIT_MAX 4.6051701859880913680f
#define VT_STRIDE 264           /* 257 padded to mult of 8 -> 16B-aligned short8 rows */
#define MT_Q 65                 /* QKV gemm M-tiles */
#define NT_Q 18                 /* QKV gemm N-tiles */

typedef unsigned short ushort;
typedef unsigned int uint;
typedef __attribute__((ext_vector_type(8))) short short8;
typedef __attribute__((ext_vector_type(4))) float f32x4;

__device__ __forceinline__ ushort f2bf_rn(float f) {
  uint u = __float_as_uint(f);
  uint r = (u + 0x7FFF + ((u >> 16) & 1)) >> 16;
  return (ushort)r;
}
__device__ __forceinline__ float bf2f(ushort h) {
  return __uint_as_float(((uint)h) << 16);
}

// bijective XCD-chunk swizzle (m204): hw block id -> work id so each XCD
// gets a contiguous chunk of work ids (consecutive ids share a B-panel).
__device__ __forceinline__ int xcd_swz(int wid, int nwg) {
  int q = nwg >> 3, r = nwg & 7;
  int xcd = wid & 7, pos = wid >> 3;
  int base = (xcd < r) ? xcd * (q + 1) : r * (q + 1) + (xcd - r) * q;
  return base + pos;
}

// ---------------- fp32 -> bf16 hi/lo split ----------------
__global__ __launch_bounds__(256)
void cvt_split(const float* __restrict__ src, ushort* __restrict__ hi,
               ushort* __restrict__ lo, int n) {
  int i = (blockIdx.x * 256 + threadIdx.x) * 4;
  if (i + 3 >= n + 3) return;
  if (i + 3 < n) {
    float4 v = *(const float4*)(src + i);
    ushort h0 = f2bf_rn(v.x), h1 = f2bf_rn(v.y), h2 = f2bf_rn(v.z), h3 = f2bf_rn(v.w);
    ushort l0 = f2bf_rn(v.x - bf2f(h0)), l1 = f2bf_rn(v.y - bf2f(h1));
    ushort l2 = f2bf_rn(v.z - bf2f(h2)), l3 = f2bf_rn(v.w - bf2f(h3));
    *(ushort4*)(hi + i) = make_ushort4(h0, h1, h2, h3);
    *(ushort4*)(lo + i) = make_ushort4(l0, l1, l2, l3);
  } else {
    for (int k = i; k < n; ++k) {
      float vv = src[k];
      ushort h = f2bf_rn(vv);
      hi[k] = h; lo[k] = f2bf_rn(vv - bf2f(h));
    }
  }
}

// ---------------- generic split-bf16 MFMA GEMM (out-proj): C = A @ W^T + bias ----------------
__global__ __launch_bounds__(256)
void gemm_mfma_split(const ushort* __restrict__ Ahi, const ushort* __restrict__ Alo,
                     const ushort* __restrict__ Bhi, const ushort* __restrict__ Blo,
                     const float* __restrict__ bias, float* __restrict__ Cout,
                     int M, int Nn, int K) {
  __shared__ __align__(16) ushort lds[4 * 128 * 32];   // 32 KB
  ushort* sAh = lds;
  ushort* sAl = lds + 4096;
  ushort* sBh = lds + 8192;
  ushort* sBl = lds + 12288;

  const int t = threadIdx.x;
  const int wave = t >> 6, lane = t & 63;
  const int wm = (wave & 1) * 64;
  const int wn = (wave >> 1) * 64;
  const int mt = (M + 127) >> 7;
  const int wid = xcd_swz(blockIdx.x, gridDim.x);
  const int m0 = (wid % mt) * 128;
  const int n0 = (wid / mt) * 128;

  const int ar = t >> 2;
  const int ac = (t & 3) * 8;
  const uint ldsOff = (uint)(t & 192) * 16;

  const int frm = lane & 15;
  const int frk = (lane >> 4) * 8;

  f32x4 acc[4][4] = {};

  for (int k0 = 0; k0 < K; k0 += 32) {
#pragma unroll
    for (int half = 0; half < 2; ++half) {
      int rA = m0 + half * 64 + ar; if (rA > M - 1) rA = M - 1;
      int rB = n0 + half * 64 + ar;
      size_t gA = (size_t)rA * K + k0 + ac;
      size_t gB = (size_t)rB * K + k0 + ac;
      uint so = (uint)half * 4096 + ldsOff;
      __builtin_amdgcn_global_load_lds(
          (const __attribute__((address_space(1))) void*)(Ahi + gA),
          (__attribute__((address_space(3))) void*)((char*)sAh + so), 16, 0, 0);
      __builtin_amdgcn_global_load_lds(
          (const __attribute__((address_space(1))) void*)(Alo + gA),
          (__attribute__((address_space(3))) void*)((char*)sAl + so), 16, 0, 0);
      __builtin_amdgcn_global_load_lds(
          (const __attribute__((address_space(1))) void*)(Bhi + gB),
          (__attribute__((address_space(3))) void*)((char*)sBh + so), 16, 0, 0);
      __builtin_amdgcn_global_load_lds(
          (const __attribute__((address_space(1))) void*)(Blo + gB),
          (__attribute__((address_space(3))) void*)((char*)sBl + so), 16, 0, 0);
    }
    __syncthreads();

    short8 ah[4], al[4], bh[4], bl[4];
#pragma unroll
    for (int i = 0; i < 4; ++i) {
      int r = wm + i * 16 + frm;
      ah[i] = *(const short8*)(sAh + r * 32 + frk);
      al[i] = *(const short8*)(sAl + r * 32 + frk);
      int c = wn + i * 16 + frm;
      bh[i] = *(const short8*)(sBh + c * 32 + frk);
      bl[i] = *(const short8*)(sBl + c * 32 + frk);
    }
#pragma unroll
    for (int i = 0; i < 4; ++i)
#pragma unroll
      for (int j = 0; j < 4; ++j) {
        acc[i][j] = __builtin_amdgcn_mfma_f32_16x16x32_bf16(ah[i], bh[j], acc[i][j], 0, 0, 0);
        acc[i][j] = __builtin_amdgcn_mfma_f32_16x16x32_bf16(ah[i], bl[j], acc[i][j], 0, 0, 0);
        acc[i][j] = __builtin_amdgcn_mfma_f32_16x16x32_bf16(al[i], bh[j], acc[i][j], 0, 0, 0);
      }
    __syncthreads();
  }

  const int ecol = lane & 15;
#pragma unroll
  for (int j = 0; j < 4; ++j) {
    int col = n0 + wn + j * 16 + ecol;
    float bv = bias[col];
#pragma unroll
    for (int i = 0; i < 4; ++i) {
      int rbase = m0 + wm + i * 16 + (lane >> 4) * 4;
#pragma unroll
      for (int r = 0; r < 4; ++r) {
        int row = rbase + r;
        if (row < M) Cout[(size_t)row * Nn + col] = acc[i][j][r] + bv;
      }
    }
  }
}

// ---------------- fused QKV GEMM: x @ Win^T + b -> normalized q/k bf16 splits + v fp32 ----------------
// Same main loop; epilogue computes per-row L2 norm for q/k sections in-register
// (wave's 64-col block == exactly one head) and writes [b][l][64] layouts directly.
__global__ __launch_bounds__(256)
void gemm_qkv_fused(const ushort* __restrict__ Ahi, const ushort* __restrict__ Alo,
                    const ushort* __restrict__ Bhi, const ushort* __restrict__ Blo,
                    const float* __restrict__ bias,
                    ushort* __restrict__ qhi, ushort* __restrict__ qlo,
                    ushort* __restrict__ khi, ushort* __restrict__ klo,
                    float* __restrict__ vout) {
  __shared__ __align__(16) ushort lds[4 * 128 * 32];   // 32 KB
  ushort* sAh = lds;
  ushort* sAl = lds + 4096;
  ushort* sBh = lds + 8192;
  ushort* sBl = lds + 12288;

  const int K = C_DIM, M = M_TOK;
  const int t = threadIdx.x;
  const int wave = t >> 6, lane = t & 63;
  const int wm = (wave & 1) * 64;
  const int wn = (wave >> 1) * 64;
  const int wid = xcd_swz(blockIdx.x, MT_Q * NT_Q);
  const int m0 = (wid % MT_Q) * 128;
  const int n0 = (wid / MT_Q) * 128;

  const int ar = t >> 2;
  const int ac = (t & 3) * 8;
  const uint ldsOff = (uint)(t & 192) * 16;

  const int frm = lane & 15;
  const int frk = (lane >> 4) * 8;

  f32x4 acc[4][4] = {};

  for (int k0 = 0; k0 < K; k0 += 32) {
#pragma unroll
    for (int half = 0; half < 2; ++half) {
      int rA = m0 + half * 64 + ar; if (rA > M - 1) rA = M - 1;
      int rB = n0 + half * 64 + ar;
      size_t gA = (size_t)rA * K + k0 + ac;
      size_t gB = (size_t)rB * K + k0 + ac;
      uint so = (uint)half * 4096 + ldsOff;
      __builtin_amdgcn_global_load_lds(
          (const __attribute__((address_space(1))) void*)(Ahi + gA),
          (__attribute__((address_space(3))) void*)((char*)sAh + so), 16, 0, 0);
      __builtin_amdgcn_global_load_lds(
          (const __attribute__((address_space(1))) void*)(Alo + gA),
          (__attribute__((address_space(3))) void*)((char*)sAl + so), 16, 0, 0);
      __builtin_amdgcn_global_load_lds(
          (const __attribute__((address_space(1))) void*)(Bhi + gB),
          (__attribute__((address_space(3))) void*)((char*)sBh + so), 16, 0, 0);
      __builtin_amdgcn_global_load_lds(
          (const __attribute__((address_space(1))) void*)(Blo + gB),
          (__attribute__((address_space(3))) void*)((char*)sBl + so), 16, 0, 0);
    }
    __syncthreads();

    short8 ah[4], al[4], bh[4], bl[4];
#pragma unroll
    for (int i = 0; i < 4; ++i) {
      int r = wm + i * 16 + frm;
      ah[i] = *(const short8*)(sAh + r * 32 + frk);
      al[i] = *(const short8*)(sAl + r * 32 + frk);
      int c = wn + i * 16 + frm;
      bh[i] = *(const short8*)(sBh + c * 32 + frk);
      bl[i] = *(const short8*)(sBl + c * 32 + frk);
    }
#pragma unroll
    for (int i = 0; i < 4; ++i)
#pragma unroll
      for (int j = 0; j < 4; ++j) {
        acc[i][j] = __builtin_amdgcn_mfma_f32_16x16x32_bf16(ah[i], bh[j], acc[i][j], 0, 0, 0);
        acc[i][j] = __builtin_amdgcn_mfma_f32_16x16x32_bf16(ah[i], bl[j], acc[i][j], 0, 0, 0);
        acc[i][j] = __builtin_amdgcn_mfma_f32_16x16x32_bf16(al[i], bh[j], acc[i][j], 0, 0, 0);
      }
    __syncthreads();
  }

  // ---- fused epilogue: bias + (norm for q/k) + split-write in [b][l][64] ----
  const int c0 = lane & 15, g = lane >> 4;
  const int colBase = n0 + wn;                 // multiple of 64 -> one head
  const int sect = colBase / C_DIM;            // 0:q 1:k 2:v
  const int hh = (colBase - sect * C_DIM) >> 6;
  float bv[4];
#pragma unroll
  for (int j = 0; j < 4; ++j) bv[j] = bias[colBase + j * 16 + c0];

#pragma unroll
  for (int i = 0; i < 4; ++i) {
#pragma unroll
    for (int r = 0; r < 4; ++r) {
      const int row = m0 + wm + i * 16 + g * 4 + r;
      float lv[4];
#pragma unroll
      for (int j = 0; j < 4; ++j) lv[j] = acc[i][j][r] + bv[j];
      if (sect == 2) {
        if (row < M) {
          int l = row >> 5, n = row & 31;
          size_t ob = ((size_t)((n * N_H + hh) * L_TOK + l)) * HD;
#pragma unroll
          for (int j = 0; j < 4; ++j) vout[ob + j * 16 + c0] = lv[j];
        }
      } else {
        float ss = lv[0] * lv[0] + lv[1] * lv[1] + lv[2] * lv[2] + lv[3] * lv[3];
        ss += __shfl_xor(ss, 1);
        ss += __shfl_xor(ss, 2);
        ss += __shfl_xor(ss, 4);
        ss += __shfl_xor(ss, 8);
        float inv = 1.0f / fmaxf(sqrtf(ss), 1e-12f);
        if (row < M) {
          int l = row >> 5, n = row & 31;
          size_t ob = ((size_t)((n * N_H + hh) * L_TOK + l)) * HD;
          ushort* dh = sect ? khi : qhi;
          ushort* dl = sect ? klo : qlo;
#pragma unroll
          for (int j = 0; j < 4; ++j) {
            float val = lv[j] * inv;
            ushort hv = f2bf_rn(val);
            dh[ob + j * 16 + c0] = hv;
            dl[ob + j * 16 + c0] = f2bf_rn(val - bf2f(hv));
          }
        }
      }
    }
  }
}

// ---------------- V transpose: v[b][l][64] fp32 -> vt{hi,lo}[b][64][VT_STRIDE] bf16 ----------------
__global__ __launch_bounds__(256)
void vt_make(const float* __restrict__ v, ushort* __restrict__ vthi,
             ushort* __restrict__ vtlo) {
  __shared__ float sT[64][65];
  const int b = blockIdx.x;
  const int t = threadIdx.x;
  const float* vb = v + (size_t)b * L_TOK * HD;
  ushort* vh = vthi + (size_t)b * HD * VT_STRIDE;
  ushort* vl = vtlo + (size_t)b * HD * VT_STRIDE;
  for (int k0 = 0; k0 < 256; k0 += 64) {
#pragma unroll
    for (int p = 0; p < 16; ++p) {
      int idx = p * 256 + t;
      int k = idx >> 6, d = idx & 63;
      sT[d][k] = vb[(size_t)(k0 + k) * HD + d];
    }
    __syncthreads();
#pragma unroll
    for (int p = 0; p < 16; ++p) {
      int idx = p * 256 + t;
      int d = idx >> 6, k = idx & 63;
      float val = sT[d][k];
      ushort h = f2bf_rn(val);
      vh[(size_t)d * VT_STRIDE + k0 + k] = h;
      vl[(size_t)d * VT_STRIDE + k0 + k] = f2bf_rn(val - bf2f(h));
    }
    __syncthreads();
  }
  if (t < HD) {
    float val = vb[(size_t)256 * HD + t];
    ushort h = f2bf_rn(val);
    vh[(size_t)t * VT_STRIDE + 256] = h;
    vl[(size_t)t * VT_STRIDE + 256] = f2bf_rn(val - bf2f(h));
  }
}

// ---------------- MFMA attention: rows 0..255, all 257 cols, softmax -> P ----------------
__global__ __launch_bounds__(256)
void attn_mfma(const ushort* __restrict__ qhi, const ushort* __restrict__ qlo,
               const ushort* __restrict__ khi, const ushort* __restrict__ klo,
               const float* __restrict__ depth, const float* __restrict__ rpe,
               const float* __restrict__ lscale, float* __restrict__ P) {
  __shared__ __align__(16) ushort sKh[256 * 72];   // 36,864 B
  __shared__ __align__(16) ushort sKl[256 * 72];
  __shared__ float cz_s[HW];
  __shared__ float txd[32], tyd[32], tzt[36];
  __shared__ float red_s[16];
  __shared__ float s256[4][16];

  const int tile = blockIdx.x;             // 0..3 -> rows tile*64..tile*64+63
  const int b = blockIdx.y;
  const int n = b / N_H, h = b - n * N_H;
  const int t = threadIdx.x;
  const int lane = t & 63, wave = t >> 6;

  // depth -> cz (bit-exact op sequence vs reference)
  float dval = depth[n * HW + t];
  float mn = dval, mx = dval;
#pragma unroll
  for (int o = 32; o > 0; o >>= 1) {
    mn = fminf(mn, __shfl_down(mn, o));
    mx = fmaxf(mx, __shfl_down(mx, o));
  }
  if (lane == 0) { red_s[wave] = mn; red_s[8 + wave] = mx; }
  __syncthreads();
  float zmin = fminf(fminf(red_s[0], red_s[1]), fminf(red_s[2], red_s[3]));
  float zmax = fmaxf(fmaxf(red_s[8], red_s[9]), fmaxf(red_s[10], red_s[11]));
  float den = zmax - zmin + 1e-8f;
  cz_s[t] = (dval - zmin) / den;
  if (t < 31) {
    int d = t - 15;
    int ix = (int)rintf((float)d * (16.0f / 15.0f));
    ix = max(-16, min(16, ix));
    txd[t] = rpe[(ix + 16) * N_H + h];
    tyd[t] = rpe[(RPE_NUM + ix + 16) * N_H + h];
  }
  if (t < RPE_NUM) tzt[t] = rpe[(2 * RPE_NUM + t) * N_H + h];
  const float scale = expf(fminf(lscale[h], LOGIT_MAX));

  // stage K rows 0..255 (bf16 hi/lo), LDS stride 72 ushorts
  const ushort* khb = khi + (size_t)b * L_TOK * HD;
  const ushort* klb = klo + (size_t)b * L_TOK * HD;
#pragma unroll
  for (int it = 0; it < 8; ++it) {
    int idx = it * 256 + t;
    int j = idx >> 3, c = (idx & 7) * 8;
    *(uint4*)(sKh + j * 72 + c) = *(const uint4*)(khb + (size_t)j * HD + c);
    *(uint4*)(sKl + j * 72 + c) = *(const uint4*)(klb + (size_t)j * HD + c);
  }
  __syncthreads();

  // Q A-frags direct from global (A[m=lane&15][k=(lane>>4)*8+j])
  const int qrow = tile * 64 + 16 * wave;
  const size_t qoff = ((size_t)b * L_TOK + qrow + (lane & 15)) * HD + (lane >> 4) * 8;
  short8 qh0 = *(const short8*)(qhi + qoff);
  short8 qh1 = *(const short8*)(qhi + qoff + 32);
  short8 ql0 = *(const short8*)(qlo + qoff);
  short8 ql1 = *(const short8*)(qlo + qoff + 32);

  f32x4 acc[16] = {};
#pragma unroll
  for (int jt = 0; jt < 16; ++jt) {
    const ushort* bp = sKh + (jt * 16 + (lane & 15)) * 72 + (lane >> 4) * 8;
    const ushort* bq = sKl + (jt * 16 + (lane & 15)) * 72 + (lane >> 4) * 8;
    short8 bh0 = *(const short8*)(bp);
    short8 bh1 = *(const short8*)(bp + 32);
    short8 bl0 = *(const short8*)(bq);
    short8 bl1 = *(const short8*)(bq + 32);
    acc[jt] = __builtin_amdgcn_mfma_f32_16x16x32_bf16(qh0, bh0, acc[jt], 0, 0, 0);
    acc[jt] = __builtin_amdgcn_mfma_f32_16x16x32_bf16(qh1, bh1, acc[jt], 0, 0, 0);
    acc[jt] = __builtin_amdgcn_mfma_f32_16x16x32_bf16(qh0, bl0, acc[jt], 0, 0, 0);
    acc[jt] = __builtin_amdgcn_mfma_f32_16x16x32_bf16(qh1, bl1, acc[jt], 0, 0, 0);
    acc[jt] = __builtin_amdgcn_mfma_f32_16x16x32_bf16(ql0, bh0, acc[jt], 0, 0, 0);
    acc[jt] = __builtin_amdgcn_mfma_f32_16x16x32_bf16(ql1, bh1, acc[jt], 0, 0, 0);
  }

  // col-256 dots via the Q frags (fp32 reconstruct), xor-reduce over k-groups
  {
    const ushort* k6h = khb + (size_t)256 * HD + (lane >> 4) * 8;
    const ushort* k6l = klb + (size_t)256 * HD + (lane >> 4) * 8;
    float p = 0.f;
#pragma unroll
    for (int j = 0; j < 8; ++j) {
      float kf0 = bf2f(k6h[j]) + bf2f(k6l[j]);
      float kf1 = bf2f(k6h[32 + j]) + bf2f(k6l[32 + j]);
      float qf0 = bf2f((ushort)qh0[j]) + bf2f((ushort)ql0[j]);
      float qf1 = bf2f((ushort)qh1[j]) + bf2f((ushort)ql1[j]);
      p = fmaf(qf0, kf0, fmaf(qf1, kf1, p));
    }
    p += __shfl_xor(p, 16);
    p += __shfl_xor(p, 32);
    if (lane < 16) s256[wave][lane] = p;
  }

  const int g = lane >> 4, c0 = lane & 15;

  // col-256 logits (uniform within 16-lane group)
  float lg6[4];
#pragma unroll
  for (int r = 0; r < 4; ++r) {
    int gi = tile * 64 + 16 * wave + 4 * g + r;
    float d6 = s256[wave][4 * g + r];
    float bz = 0.f;
    if (gi >= 1) {
      int dx = ((gi - 1) & 15) - 15;
      int dy = ((gi - 1) >> 4) - 15;
      float rz = (cz_s[gi - 1] - cz_s[255]) * 16.0f;
      int iz = (int)rintf(rz); iz = max(-16, min(16, iz));
      bz = txd[dx + 15] + tyd[dy + 15] + tzt[iz + 16];
    }
    lg6[r] = scale * d6 + bz;
  }

  // bias -> logits in place
#pragma unroll
  for (int jt = 0; jt < 16; ++jt) {
    int col = jt * 16 + c0;
#pragma unroll
    for (int r = 0; r < 4; ++r) {
      int gi = tile * 64 + 16 * wave + 4 * g + r;
      float lv = scale * acc[jt][r];
      if (col >= 1 && gi >= 1) {
        int dx = ((gi - 1) & 15) - ((col - 1) & 15);
        int dy = ((gi - 1) >> 4) - ((col - 1) >> 4);
        float rz = (cz_s[gi - 1] - cz_s[col - 1]) * 16.0f;
        int iz = (int)rintf(rz); iz = max(-16, min(16, iz));
        lv += txd[dx + 15] + tyd[dy + 15] + tzt[iz + 16];
      }
      acc[jt][r] = lv;
    }
  }

  // softmax per row (rows live in (g,r); reduce across low-4 lane bits)
  float* Pb_ = P + (size_t)b * L_TOK * L_TOK;
#pragma unroll
  for (int r = 0; r < 4; ++r) {
    int gi = tile * 64 + 16 * wave + 4 * g + r;
    float m = acc[0][r];
#pragma unroll
    for (int jt = 1; jt < 16; ++jt) m = fmaxf(m, acc[jt][r]);
#pragma unroll
    for (int o = 1; o < 16; o <<= 1) m = fmaxf(m, __shfl_xor(m, o));
    m = fmaxf(m, lg6[r]);
    float s = 0.f;
#pragma unroll
    for (int jt = 0; jt < 16; ++jt) {
      float e = __expf(acc[jt][r] - m);
      acc[jt][r] = e;
      s += e;
    }
#pragma unroll
    for (int o = 1; o < 16; o <<= 1) s += __shfl_xor(s, o);
    float e6 = __expf(lg6[r] - m);
    float inv = 1.0f / (s + e6);
    float* Prow = Pb_ + (size_t)gi * L_TOK;
#pragma unroll
    for (int jt = 0; jt < 16; ++jt)
      Prow[jt * 16 + c0] = acc[jt][r] * inv;
    if (c0 == 0) Prow[256] = e6 * inv;
  }
}

// ---------------- row 256: plain VALU dot + softmax ----------------
__global__ __launch_bounds__(256)
void attn_row256(const ushort* __restrict__ qhi, const ushort* __restrict__ qlo,
                 const ushort* __restrict__ khi, const ushort* __restrict__ klo,
                 const float* __restrict__ depth, const float* __restrict__ rpe,
                 const float* __restrict__ lscale, float* __restrict__ P) {
  __shared__ float qs[HD];
  __shared__ float cz_s[HW];
  __shared__ float txd[32], tyd[32], tzt[36];
  __shared__ float red_s[16];
  __shared__ float lg6_sh;

  const int b = blockIdx.x;
  const int n = b / N_H, h = b - n * N_H;
  const int t = threadIdx.x;
  const int lane = t & 63, wave = t >> 6;

  float dval = depth[n * HW + t];
  float mn = dval, mx = dval;
#pragma unroll
  for (int o = 32; o > 0; o >>= 1) {
    mn = fminf(mn, __shfl_down(mn, o));
    mx = fmaxf(mx, __shfl_down(mx, o));
  }
  if (lane == 0) { red_s[wave] = mn; red_s[8 + wave] = mx; }
  __syncthreads();
  float zmin = fminf(fminf(red_s[0], red_s[1]), fminf(red_s[2], red_s[3]));
  float zmax = fmaxf(fmaxf(red_s[8], red_s[9]), fmaxf(red_s[10], red_s[11]));
  float den = zmax - zmin + 1e-8f;
  cz_s[t] = (dval - zmin) / den;
  if (t < 31) {
    int d = t - 15;
    int ix = (int)rintf((float)d * (16.0f / 15.0f));
    ix = max(-16, min(16, ix));
    txd[t] = rpe[(ix + 16) * N_H + h];
    tyd[t] = rpe[(RPE_NUM + ix + 16) * N_H + h];
  }
  if (t < RPE_NUM) tzt[t] = rpe[(2 * RPE_NUM + t) * N_H + h];
  const float scale = expf(fminf(lscale[h], LOGIT_MAX));

  const size_t q6 = ((size_t)b * L_TOK + 256) * HD;
  if (t < HD) qs[t] = bf2f(qhi[q6 + t]) + bf2f(qlo[q6 + t]);
  __syncthreads();

  // key j = t
  const ushort* krh = khi + ((size_t)b * L_TOK + t) * HD;
  const ushort* krl = klo + ((size_t)b * L_TOK + t) * HD;
  float dot = 0.f;
#pragma unroll
  for (int c = 0; c < HD; c += 8) {
    ushort4 hv0 = *(const ushort4*)(krh + c);
    ushort4 hv1 = *(const ushort4*)(krh + c + 4);
    ushort4 lv0 = *(const ushort4*)(krl + c);
    ushort4 lv1 = *(const ushort4*)(krl + c + 4);
    dot = fmaf(bf2f(hv0.x) + bf2f(lv0.x), qs[c + 0], dot);
    dot = fmaf(bf2f(hv0.y) + bf2f(lv0.y), qs[c + 1], dot);
    dot = fmaf(bf2f(hv0.z) + bf2f(lv0.z), qs[c + 2], dot);
    dot = fmaf(bf2f(hv0.w) + bf2f(lv0.w), qs[c + 3], dot);
    dot = fmaf(bf2f(hv1.x) + bf2f(lv1.x), qs[c + 4], dot);
    dot = fmaf(bf2f(hv1.y) + bf2f(lv1.y), qs[c + 5], dot);
    dot = fmaf(bf2f(hv1.z) + bf2f(lv1.z), qs[c + 6], dot);
    dot = fmaf(bf2f(hv1.w) + bf2f(lv1.w), qs[c + 7], dot);
  }

  float lg;
  {
    float bsum = 0.f;
    if (t >= 1) {
      int dx = 15 - ((t - 1) & 15);
      int dy = 15 - ((t - 1) >> 4);
      float rz = (cz_s[255] - cz_s[t - 1]) * 16.0f;
      int iz = (int)rintf(rz); iz = max(-16, min(16, iz));
      bsum = txd[dx + 15] + tyd[dy + 15] + tzt[iz + 16];
    }
    lg = scale * dot + bsum;
  }

  // key 256 by wave 0
  if (wave == 0) {
    const ushort* k6h = khi + q6;
    const ushort* k6l = klo + q6;
    float pp = (bf2f(k6h[lane]) + bf2f(k6l[lane])) * qs[lane];
#pragma unroll
    for (int o = 32; o > 0; o >>= 1) pp += __shfl_down(pp, o);
    if (lane == 0) {
      // bias(256,256): dx=dy=0, rz=0 -> iz=0
      float bz = txd[15] + tyd[15] + tzt[16];
      lg6_sh = scale * pp + bz;
    }
  }

  // block softmax over 257
  float m = lg;
#pragma unroll
  for (int o = 32; o > 0; o >>= 1) m = fmaxf(m, __shfl_down(m, o));
  if (lane == 0) red_s[wave] = m;
  __syncthreads();
  float M = fmaxf(fmaxf(red_s[0], red_s[1]), fmaxf(red_s[2], red_s[3]));
  M = fmaxf(M, lg6_sh);
  float e = __expf(lg - M);
  float s = e;
#pragma unroll
  for (int o = 32; o > 0; o >>= 1) s += __shfl_down(s, o);
  if (lane == 0) red_s[8 + wave] = s;
  __syncthreads();
  float e6 = __expf(lg6_sh - M);
  float S = (red_s[8] + red_s[9]) + (red_s[10] + red_s[11]) + e6;
  float inv = 1.0f / S;
  float* Prow = P + (size_t)b * L_TOK * L_TOK + (size_t)256 * L_TOK;
  Prow[t] = e * inv;
  if (t == 0) Prow[256] = e6 * inv;
}

// ---------------- PV via MFMA -> bf16 hi/lo A-matrix for out-proj ----------------
// A = P rows (fp32 -> bf16 hi/lo in regs), B = V^T from vt{hi,lo}. Epilogue writes
// the out-proj GEMM's A operand (ahi/alo) directly — no fp32 round-trip.
__global__ __launch_bounds__(256)
void pv_mfma(const float* __restrict__ P, const ushort* __restrict__ vthi,
             const ushort* __restrict__ vtlo, const float* __restrict__ v,
             ushort* __restrict__ ahi, ushort* __restrict__ alo) {
  const int b = blockIdx.y;
  const int n = b / N_H, h = b - n * N_H;
  const int t = threadIdx.x;
  const int lane = t & 63, wave = t >> 6;
  const int rbase = blockIdx.x * 128 + wave * 32;   // 32 rows per wave
  const float* Pb = P + (size_t)b * L_TOK * L_TOK;
  const ushort* vh = vthi + (size_t)b * HD * VT_STRIDE;
  const ushort* vl = vtlo + (size_t)b * HD * VT_STRIDE;

  const int fm = lane & 15, fk = (lane >> 4) * 8;
  f32x4 acc[2][4] = {};

  for (int k0 = 0; k0 < 256; k0 += 32) {
    short8 ah[2], al[2], bh[4], bl[4];
#pragma unroll
    for (int i = 0; i < 2; ++i) {
      const float* pr = Pb + (size_t)(rbase + i * 16 + fm) * L_TOK + k0 + fk;
#pragma unroll
      for (int j = 0; j < 8; ++j) {
        float pv_ = pr[j];
        ushort hh = f2bf_rn(pv_);
        ah[i][j] = (short)hh;
        al[i][j] = (short)f2bf_rn(pv_ - bf2f(hh));
      }
    }
#pragma unroll
    for (int j = 0; j < 4; ++j) {
      const ushort* bp = vh + (size_t)(j * 16 + fm) * VT_STRIDE + k0 + fk;
      const ushort* bq = vl + (size_t)(j * 16 + fm) * VT_STRIDE + k0 + fk;
      bh[j] = *(const short8*)bp;
      bl[j] = *(const short8*)bq;
    }
#pragma unroll
    for (int i = 0; i < 2; ++i)
#pragma unroll
      for (int j = 0; j < 4; ++j) {
        acc[i][j] = __builtin_amdgcn_mfma_f32_16x16x32_bf16(ah[i], bh[j], acc[i][j], 0, 0, 0);
        acc[i][j] = __builtin_amdgcn_mfma_f32_16x16x32_bf16(ah[i], bl[j], acc[i][j], 0, 0, 0);
        acc[i][j] = __builtin_amdgcn_mfma_f32_16x16x32_bf16(al[i], bh[j], acc[i][j], 0, 0, 0);
        acc[i][j] = __builtin_amdgcn_mfma_f32_16x16x32_bf16(al[i], bl[j], acc[i][j], 0, 0, 0);
      }
  }

  // k = 256 tail, exact fp32 (v is [b][l][64])
  const int g = lane >> 4;
  float v6[4];
#pragma unroll
  for (int j = 0; j < 4; ++j)
    v6[j] = v[((size_t)b * L_TOK + 256) * HD + j * 16 + fm];
#pragma unroll
  for (int i = 0; i < 2; ++i)
#pragma unroll
    for (int r = 0; r < 4; ++r) {
      int row = rbase + i * 16 + g * 4 + r;
      float p6 = Pb[(size_t)row * L_TOK + 256];
#pragma unroll
      for (int j = 0; j < 4; ++j) acc[i][j][r] += p6 * v6[j];
    }

  // write A[row=l*32+n][col=h*64+d] as bf16 hi/lo
#pragma unroll
  for (int i = 0; i < 2; ++i)
#pragma unroll
    for (int r = 0; r < 4; ++r) {
      int row = rbase + i * 16 + g * 4 + r;
      size_t o = ((size_t)row * N_B + n) * C_DIM + h * HD;
#pragma unroll
      for (int j = 0; j < 4; ++j) {
        float val = acc[i][j][r];
        ushort hv = f2bf_rn(val);
        ahi[o + j * 16 + fm] = hv;
        alo[o + j * 16 + fm] = f2bf_rn(val - bf2f(hv));
      }
    }

  // row 256 (exact fp32), done once per b by block.x==0
  if (blockIdx.x == 0 && t < HD) {
    const float* Prow = Pb + (size_t)256 * L_TOK;
    const float* vb = v + (size_t)b * L_TOK * HD;
    float sum = 0.f;
    for (int k = 0; k < L_TOK; ++k)
      sum = fmaf(Prow[k], vb[(size_t)k * HD + t], sum);
    size_t o = ((size_t)256 * N_B + n) * C_DIM + h * HD + t;
    ushort hv = f2bf_rn(sum);
    ahi[o] = hv;
    alo[o] = f2bf_rn(sum - bf2f(hv));
  }
}

extern "C" void kernel_launch(void* const* d_in, const int* in_sizes, int n_in,
                              void* d_out, int out_size, void* d_ws, size_t ws_size,
                              hipStream_t stream) {
  const float* x      = (const float*)d_in[0];
  const float* depth  = (const float*)d_in[1];
  const float* w_in   = (const float*)d_in[2];
  const float* b_in   = (const float*)d_in[3];
  const float* w_out  = (const float*)d_in[4];
  const float* b_out  = (const float*)d_in[5];
  const float* rpe    = (const float*)d_in[6];
  const float* lscale = (const float*)d_in[7];
  float* out = (float*)d_out;
  float* ws = (float*)d_ws;

  // layout (float units). Lifetimes:
  //   xhi/xlo [0..6.3M)       : cvt(x) -> QKV gemm; dead after -> reused as ahi/alo by pv
  //   vthi/vtlo [6.3M..12.8M) : vt_make -> pv; dead after
  //   v [18.9M..25.3M)        : QKV gemm -> vt_make, pv
  //   qhi..klo [25.3M..37.9M) : QKV gemm -> attn
  //   w splits [37.9M..40.3M) : persistent
  ushort* xhi  = (ushort*)ws;                   // 6,316,032 ushorts
  ushort* xlo  = xhi + 6316032;
  ushort* vthi = (ushort*)(ws + 6316032);       // 6,488,064 ushorts each
  ushort* vtlo = vthi + 6488064;
  float*  v    = ws + 18948096;                 // 6,316,032 floats
  ushort* qhi  = (ushort*)(ws + 25264128);      // 6,316,032 ushorts each
  ushort* qlo  = qhi + 6316032;
  ushort* khi  = qlo + 6316032;
  ushort* klo  = khi + 6316032;
  ushort* wihi = (ushort*)(ws + 37896192);      // 1,769,472 each
  ushort* wilo = wihi + 1769472;
  ushort* wohi = wilo + 1769472;                // 589,824 each
  ushort* wolo = wohi + 589824;
  ushort* ahi  = xhi;                           // overlay: x splits dead after QKV gemm
  ushort* alo  = xlo;
  float* Pout = out + 6316032;

  cvt_split<<<6168, 256, 0, stream>>>(x, xhi, xlo, 6316032);
  cvt_split<<<1728, 256, 0, stream>>>(w_in, wihi, wilo, 1769472);
  cvt_split<<<576, 256, 0, stream>>>(w_out, wohi, wolo, 589824);

  gemm_qkv_fused<<<MT_Q * NT_Q, 256, 0, stream>>>(xhi, xlo, wihi, wilo, b_in,
                                                  qhi, qlo, khi, klo, v);
  vt_make<<<BH, 256, 0, stream>>>(v, vthi, vtlo);
  attn_mfma<<<dim3(4, BH), 256, 0, stream>>>(qhi, qlo, khi, klo, depth, rpe, lscale, Pout);
  attn_row256<<<BH, 256, 0, stream>>>(qhi, qlo, khi, klo, depth, rpe, lscale, Pout);
  pv_mfma<<<dim3(2, BH), 256, 0, stream>>>(Pout, vthi, vtlo, v, ahi, alo);

  gemm_mfma_split<<<65 * 6, 256, 0, stream>>>(ahi, alo, wohi, wolo, b_out, out,
                                              M_TOK, C_DIM, C_DIM);
}

// Round 3
// 494.139 us; speedup vs baseline: 1.1908x; 1.0160x over previous
//
#include <hip/hip_runtime.h>
#include <math.h>

#define L_TOK 257
#define N_B 32
#define C_DIM 768
#define N_H 12
#define HD 64
#define BH (N_B * N_H)          /* 384 */
#define M_TOK (L_TOK * N_B)     /* 8224 */
#define HW 256
#define RPE_NUM 33
#define LOGIT_MAX 4.6051701859880913680f
#define VT_STRIDE 264           /* 257 padded to mult of 8 -> 16B-aligned short8 rows */
#define MT_Q 65                 /* gemm M-tiles (128-row) */
#define NT_Q 18                 /* QKV gemm N-tiles (128-col) */
#define NT_O 12                 /* out-proj N-tiles (64-col) */

typedef unsigned short ushort;
typedef unsigned int uint;
typedef __attribute__((ext_vector_type(8))) short short8;
typedef __attribute__((ext_vector_type(4))) float f32x4;

__device__ __forceinline__ ushort f2bf_rn(float f) {
  uint u = __float_as_uint(f);
  uint r = (u + 0x7FFF + ((u >> 16) & 1)) >> 16;
  return (ushort)r;
}
__device__ __forceinline__ float bf2f(ushort h) {
  return __uint_as_float(((uint)h) << 16);
}

// bijective XCD-chunk swizzle (m204): hw block id -> work id so each XCD
// gets a contiguous chunk of work ids.
__device__ __forceinline__ int xcd_swz(int wid, int nwg) {
  int q = nwg >> 3, r = nwg & 7;
  int xcd = wid & 7, pos = wid >> 3;
  int base = (xcd < r) ? xcd * (q + 1) : r * (q + 1) + (xcd - r) * q;
  return base + pos;
}

// 2-D supertile map: contiguous wid-chunks cover 8-m-tile x NT-n-tile
// rectangles, so each XCD's A-slice (~3.1 MB) stays L2-resident.
// Returns m-tile base row (x128) and n-tile index.
__device__ __forceinline__ void tile_map(int bid, int MT, int NT, int nwg,
                                         int& m0, int& nt) {
  int wid = xcd_swz(bid, nwg);
  int per = 8 * NT;
  int s = wid / per;
  int rem = wid - s * per;
  int msz = MT - s * 8; if (msz > 8) msz = 8;
  int mi = rem % msz, ni = rem / msz;
  m0 = (s * 8 + mi) * 128;
  nt = ni;
}

// ---------------- fp32 -> bf16 hi/lo split ----------------
__global__ __launch_bounds__(256)
void cvt_split(const float* __restrict__ src, ushort* __restrict__ hi,
               ushort* __restrict__ lo, int n) {
  int i = (blockIdx.x * 256 + threadIdx.x) * 4;
  if (i + 3 >= n + 3) return;
  if (i + 3 < n) {
    float4 v = *(const float4*)(src + i);
    ushort h0 = f2bf_rn(v.x), h1 = f2bf_rn(v.y), h2 = f2bf_rn(v.z), h3 = f2bf_rn(v.w);
    ushort l0 = f2bf_rn(v.x - bf2f(h0)), l1 = f2bf_rn(v.y - bf2f(h1));
    ushort l2 = f2bf_rn(v.z - bf2f(h2)), l3 = f2bf_rn(v.w - bf2f(h3));
    *(ushort4*)(hi + i) = make_ushort4(h0, h1, h2, h3);
    *(ushort4*)(lo + i) = make_ushort4(l0, l1, l2, l3);
  } else {
    for (int k = i; k < n; ++k) {
      float vv = src[k];
      ushort h = f2bf_rn(vv);
      hi[k] = h; lo[k] = f2bf_rn(vv - bf2f(h));
    }
  }
}

// ---------------- out-proj GEMM, 128x64 tiles: C = A @ W^T + bias ----------------
// 780 blocks (vs 390 at 128x128) -> ~3 blocks/CU so staging latency is hidden.
__global__ __launch_bounds__(256)
void gemm_out_n64(const ushort* __restrict__ Ahi, const ushort* __restrict__ Alo,
                  const ushort* __restrict__ Bhi, const ushort* __restrict__ Blo,
                  const float* __restrict__ bias, float* __restrict__ Cout) {
  __shared__ __align__(16) ushort lds[12288];   // 24 KB
  ushort* sAh = lds;            // 128x32
  ushort* sAl = lds + 4096;     // 128x32
  ushort* sBh = lds + 8192;     // 64x32
  ushort* sBl = lds + 10240;    // 64x32

  const int M = M_TOK, Nn = C_DIM, K = C_DIM;
  const int t = threadIdx.x;
  const int wave = t >> 6, lane = t & 63;
  const int wm = (wave & 1) * 64;
  const int wn = (wave >> 1) * 32;
  int m0, nt;
  tile_map(blockIdx.x, MT_Q, NT_O, MT_Q * NT_O, m0, nt);
  const int n0 = nt * 64;

  const int ar = t >> 2;
  const int ac = (t & 3) * 8;
  const uint ldsOff = (uint)(t & 192) * 16;

  const int frm = lane & 15;
  const int frk = (lane >> 4) * 8;

  f32x4 acc[4][2] = {};

  for (int k0 = 0; k0 < K; k0 += 32) {
#pragma unroll
    for (int half = 0; half < 2; ++half) {
      int rA = m0 + half * 64 + ar; if (rA > M - 1) rA = M - 1;
      size_t gA = (size_t)rA * K + k0 + ac;
      uint so = (uint)half * 4096 + ldsOff;
      __builtin_amdgcn_global_load_lds(
          (const __attribute__((address_space(1))) void*)(Ahi + gA),
          (__attribute__((address_space(3))) void*)((char*)sAh + so), 16, 0, 0);
      __builtin_amdgcn_global_load_lds(
          (const __attribute__((address_space(1))) void*)(Alo + gA),
          (__attribute__((address_space(3))) void*)((char*)sAl + so), 16, 0, 0);
    }
    {
      int rB = n0 + ar;
      size_t gB = (size_t)rB * K + k0 + ac;
      __builtin_amdgcn_global_load_lds(
          (const __attribute__((address_space(1))) void*)(Bhi + gB),
          (__attribute__((address_space(3))) void*)((char*)sBh + ldsOff), 16, 0, 0);
      __builtin_amdgcn_global_load_lds(
          (const __attribute__((address_space(1))) void*)(Blo + gB),
          (__attribute__((address_space(3))) void*)((char*)sBl + ldsOff), 16, 0, 0);
    }
    __syncthreads();

    short8 ah[4], al[4], bh[2], bl[2];
#pragma unroll
    for (int i = 0; i < 4; ++i) {
      int r = wm + i * 16 + frm;
      ah[i] = *(const short8*)(sAh + r * 32 + frk);
      al[i] = *(const short8*)(sAl + r * 32 + frk);
    }
#pragma unroll
    for (int j = 0; j < 2; ++j) {
      int c = wn + j * 16 + frm;
      bh[j] = *(const short8*)(sBh + c * 32 + frk);
      bl[j] = *(const short8*)(sBl + c * 32 + frk);
    }
#pragma unroll
    for (int i = 0; i < 4; ++i)
#pragma unroll
      for (int j = 0; j < 2; ++j) {
        acc[i][j] = __builtin_amdgcn_mfma_f32_16x16x32_bf16(ah[i], bh[j], acc[i][j], 0, 0, 0);
        acc[i][j] = __builtin_amdgcn_mfma_f32_16x16x32_bf16(ah[i], bl[j], acc[i][j], 0, 0, 0);
        acc[i][j] = __builtin_amdgcn_mfma_f32_16x16x32_bf16(al[i], bh[j], acc[i][j], 0, 0, 0);
      }
    __syncthreads();
  }

  const int ecol = lane & 15;
#pragma unroll
  for (int j = 0; j < 2; ++j) {
    int col = n0 + wn + j * 16 + ecol;
    float bv = bias[col];
#pragma unroll
    for (int i = 0; i < 4; ++i) {
      int rbase = m0 + wm + i * 16 + (lane >> 4) * 4;
#pragma unroll
      for (int r = 0; r < 4; ++r) {
        int row = rbase + r;
        if (row < M) Cout[(size_t)row * Nn + col] = acc[i][j][r] + bv;
      }
    }
  }
}

// ---------------- fused QKV GEMM: x @ Win^T + b -> normalized q/k bf16 splits + v fp32 ----------------
__global__ __launch_bounds__(256)
void gemm_qkv_fused(const ushort* __restrict__ Ahi, const ushort* __restrict__ Alo,
                    const ushort* __restrict__ Bhi, const ushort* __restrict__ Blo,
                    const float* __restrict__ bias,
                    ushort* __restrict__ qhi, ushort* __restrict__ qlo,
                    ushort* __restrict__ khi, ushort* __restrict__ klo,
                    float* __restrict__ vout) {
  __shared__ __align__(16) ushort lds[4 * 128 * 32];   // 32 KB
  ushort* sAh = lds;
  ushort* sAl = lds + 4096;
  ushort* sBh = lds + 8192;
  ushort* sBl = lds + 12288;

  const int K = C_DIM, M = M_TOK;
  const int t = threadIdx.x;
  const int wave = t >> 6, lane = t & 63;
  const int wm = (wave & 1) * 64;
  const int wn = (wave >> 1) * 64;
  int m0, nt;
  tile_map(blockIdx.x, MT_Q, NT_Q, MT_Q * NT_Q, m0, nt);
  const int n0 = nt * 128;

  const int ar = t >> 2;
  const int ac = (t & 3) * 8;
  const uint ldsOff = (uint)(t & 192) * 16;

  const int frm = lane & 15;
  const int frk = (lane >> 4) * 8;

  f32x4 acc[4][4] = {};

  for (int k0 = 0; k0 < K; k0 += 32) {
#pragma unroll
    for (int half = 0; half < 2; ++half) {
      int rA = m0 + half * 64 + ar; if (rA > M - 1) rA = M - 1;
      int rB = n0 + half * 64 + ar;
      size_t gA = (size_t)rA * K + k0 + ac;
      size_t gB = (size_t)rB * K + k0 + ac;
      uint so = (uint)half * 4096 + ldsOff;
      __builtin_amdgcn_global_load_lds(
          (const __attribute__((address_space(1))) void*)(Ahi + gA),
          (__attribute__((address_space(3))) void*)((char*)sAh + so), 16, 0, 0);
      __builtin_amdgcn_global_load_lds(
          (const __attribute__((address_space(1))) void*)(Alo + gA),
          (__attribute__((address_space(3))) void*)((char*)sAl + so), 16, 0, 0);
      __builtin_amdgcn_global_load_lds(
          (const __attribute__((address_space(1))) void*)(Bhi + gB),
          (__attribute__((address_space(3))) void*)((char*)sBh + so), 16, 0, 0);
      __builtin_amdgcn_global_load_lds(
          (const __attribute__((address_space(1))) void*)(Blo + gB),
          (__attribute__((address_space(3))) void*)((char*)sBl + so), 16, 0, 0);
    }
    __syncthreads();

    short8 ah[4], al[4], bh[4], bl[4];
#pragma unroll
    for (int i = 0; i < 4; ++i) {
      int r = wm + i * 16 + frm;
      ah[i] = *(const short8*)(sAh + r * 32 + frk);
      al[i] = *(const short8*)(sAl + r * 32 + frk);
      int c = wn + i * 16 + frm;
      bh[i] = *(const short8*)(sBh + c * 32 + frk);
      bl[i] = *(const short8*)(sBl + c * 32 + frk);
    }
#pragma unroll
    for (int i = 0; i < 4; ++i)
#pragma unroll
      for (int j = 0; j < 4; ++j) {
        acc[i][j] = __builtin_amdgcn_mfma_f32_16x16x32_bf16(ah[i], bh[j], acc[i][j], 0, 0, 0);
        acc[i][j] = __builtin_amdgcn_mfma_f32_16x16x32_bf16(ah[i], bl[j], acc[i][j], 0, 0, 0);
        acc[i][j] = __builtin_amdgcn_mfma_f32_16x16x32_bf16(al[i], bh[j], acc[i][j], 0, 0, 0);
      }
    __syncthreads();
  }

  // ---- fused epilogue: bias + (norm for q/k) + split-write in [b][l][64] ----
  const int c0 = lane & 15, g = lane >> 4;
  const int colBase = n0 + wn;                 // multiple of 64 -> one head
  const int sect = colBase / C_DIM;            // 0:q 1:k 2:v
  const int hh = (colBase - sect * C_DIM) >> 6;
  float bv[4];
#pragma unroll
  for (int j = 0; j < 4; ++j) bv[j] = bias[colBase + j * 16 + c0];

#pragma unroll
  for (int i = 0; i < 4; ++i) {
#pragma unroll
    for (int r = 0; r < 4; ++r) {
      const int row = m0 + wm + i * 16 + g * 4 + r;
      float lv[4];
#pragma unroll
      for (int j = 0; j < 4; ++j) lv[j] = acc[i][j][r] + bv[j];
      if (sect == 2) {
        if (row < M) {
          int l = row >> 5, n = row & 31;
          size_t ob = ((size_t)((n * N_H + hh) * L_TOK + l)) * HD;
#pragma unroll
          for (int j = 0; j < 4; ++j) vout[ob + j * 16 + c0] = lv[j];
        }
      } else {
        float ss = lv[0] * lv[0] + lv[1] * lv[1] + lv[2] * lv[2] + lv[3] * lv[3];
        ss += __shfl_xor(ss, 1);
        ss += __shfl_xor(ss, 2);
        ss += __shfl_xor(ss, 4);
        ss += __shfl_xor(ss, 8);
        float inv = 1.0f / fmaxf(sqrtf(ss), 1e-12f);
        if (row < M) {
          int l = row >> 5, n = row & 31;
          size_t ob = ((size_t)((n * N_H + hh) * L_TOK + l)) * HD;
          ushort* dh = sect ? khi : qhi;
          ushort* dl = sect ? klo : qlo;
#pragma unroll
          for (int j = 0; j < 4; ++j) {
            float val = lv[j] * inv;
            ushort hv = f2bf_rn(val);
            dh[ob + j * 16 + c0] = hv;
            dl[ob + j * 16 + c0] = f2bf_rn(val - bf2f(hv));
          }
        }
      }
    }
  }
}

// ---------------- V transpose: v[b][l][64] fp32 -> vt{hi,lo}[b][64][VT_STRIDE] bf16 ----------------
__global__ __launch_bounds__(256)
void vt_make(const float* __restrict__ v, ushort* __restrict__ vthi,
             ushort* __restrict__ vtlo) {
  __shared__ float sT[64][65];
  const int b = blockIdx.x;
  const int t = threadIdx.x;
  const float* vb = v + (size_t)b * L_TOK * HD;
  ushort* vh = vthi + (size_t)b * HD * VT_STRIDE;
  ushort* vl = vtlo + (size_t)b * HD * VT_STRIDE;
  for (int k0 = 0; k0 < 256; k0 += 64) {
#pragma unroll
    for (int p = 0; p < 16; ++p) {
      int idx = p * 256 + t;
      int k = idx >> 6, d = idx & 63;
      sT[d][k] = vb[(size_t)(k0 + k) * HD + d];
    }
    __syncthreads();
#pragma unroll
    for (int p = 0; p < 16; ++p) {
      int idx = p * 256 + t;
      int d = idx >> 6, k = idx & 63;
      float val = sT[d][k];
      ushort h = f2bf_rn(val);
      vh[(size_t)d * VT_STRIDE + k0 + k] = h;
      vl[(size_t)d * VT_STRIDE + k0 + k] = f2bf_rn(val - bf2f(h));
    }
    __syncthreads();
  }
  if (t < HD) {
    float val = vb[(size_t)256 * HD + t];
    ushort h = f2bf_rn(val);
    vh[(size_t)t * VT_STRIDE + 256] = h;
    vl[(size_t)t * VT_STRIDE + 256] = f2bf_rn(val - bf2f(h));
  }
}

// ---------------- MFMA attention: rows 0..255, all 257 cols, softmax -> P ----------------
__global__ __launch_bounds__(256)
void attn_mfma(const ushort* __restrict__ qhi, const ushort* __restrict__ qlo,
               const ushort* __restrict__ khi, const ushort* __restrict__ klo,
               const float* __restrict__ depth, const float* __restrict__ rpe,
               const float* __restrict__ lscale, float* __restrict__ P) {
  __shared__ __align__(16) ushort sKh[256 * 72];   // 36,864 B
  __shared__ __align__(16) ushort sKl[256 * 72];
  __shared__ float cz_s[HW];
  __shared__ float txd[32], tyd[32], tzt[36];
  __shared__ float red_s[16];
  __shared__ float s256[4][16];

  const int tile = blockIdx.x;             // 0..3 -> rows tile*64..tile*64+63
  const int b = blockIdx.y;
  const int n = b / N_H, h = b - n * N_H;
  const int t = threadIdx.x;
  const int lane = t & 63, wave = t >> 6;

  // depth -> cz (bit-exact op sequence vs reference)
  float dval = depth[n * HW + t];
  float mn = dval, mx = dval;
#pragma unroll
  for (int o = 32; o > 0; o >>= 1) {
    mn = fminf(mn, __shfl_down(mn, o));
    mx = fmaxf(mx, __shfl_down(mx, o));
  }
  if (lane == 0) { red_s[wave] = mn; red_s[8 + wave] = mx; }
  __syncthreads();
  float zmin = fminf(fminf(red_s[0], red_s[1]), fminf(red_s[2], red_s[3]));
  float zmax = fmaxf(fmaxf(red_s[8], red_s[9]), fmaxf(red_s[10], red_s[11]));
  float den = zmax - zmin + 1e-8f;
  cz_s[t] = (dval - zmin) / den;
  if (t < 31) {
    int d = t - 15;
    int ix = (int)rintf((float)d * (16.0f / 15.0f));
    ix = max(-16, min(16, ix));
    txd[t] = rpe[(ix + 16) * N_H + h];
    tyd[t] = rpe[(RPE_NUM + ix + 16) * N_H + h];
  }
  if (t < RPE_NUM) tzt[t] = rpe[(2 * RPE_NUM + t) * N_H + h];
  const float scale = expf(fminf(lscale[h], LOGIT_MAX));

  // stage K rows 0..255 (bf16 hi/lo), LDS stride 72 ushorts
  const ushort* khb = khi + (size_t)b * L_TOK * HD;
  const ushort* klb = klo + (size_t)b * L_TOK * HD;
#pragma unroll
  for (int it = 0; it < 8; ++it) {
    int idx = it * 256 + t;
    int j = idx >> 3, c = (idx & 7) * 8;
    *(uint4*)(sKh + j * 72 + c) = *(const uint4*)(khb + (size_t)j * HD + c);
    *(uint4*)(sKl + j * 72 + c) = *(const uint4*)(klb + (size_t)j * HD + c);
  }
  __syncthreads();

  // Q A-frags direct from global (A[m=lane&15][k=(lane>>4)*8+j])
  const int qrow = tile * 64 + 16 * wave;
  const size_t qoff = ((size_t)b * L_TOK + qrow + (lane & 15)) * HD + (lane >> 4) * 8;
  short8 qh0 = *(const short8*)(qhi + qoff);
  short8 qh1 = *(const short8*)(qhi + qoff + 32);
  short8 ql0 = *(const short8*)(qlo + qoff);
  short8 ql1 = *(const short8*)(qlo + qoff + 32);

  f32x4 acc[16] = {};
#pragma unroll
  for (int jt = 0; jt < 16; ++jt) {
    const ushort* bp = sKh + (jt * 16 + (lane & 15)) * 72 + (lane >> 4) * 8;
    const ushort* bq = sKl + (jt * 16 + (lane & 15)) * 72 + (lane >> 4) * 8;
    short8 bh0 = *(const short8*)(bp);
    short8 bh1 = *(const short8*)(bp + 32);
    short8 bl0 = *(const short8*)(bq);
    short8 bl1 = *(const short8*)(bq + 32);
    acc[jt] = __builtin_amdgcn_mfma_f32_16x16x32_bf16(qh0, bh0, acc[jt], 0, 0, 0);
    acc[jt] = __builtin_amdgcn_mfma_f32_16x16x32_bf16(qh1, bh1, acc[jt], 0, 0, 0);
    acc[jt] = __builtin_amdgcn_mfma_f32_16x16x32_bf16(qh0, bl0, acc[jt], 0, 0, 0);
    acc[jt] = __builtin_amdgcn_mfma_f32_16x16x32_bf16(qh1, bl1, acc[jt], 0, 0, 0);
    acc[jt] = __builtin_amdgcn_mfma_f32_16x16x32_bf16(ql0, bh0, acc[jt], 0, 0, 0);
    acc[jt] = __builtin_amdgcn_mfma_f32_16x16x32_bf16(ql1, bh1, acc[jt], 0, 0, 0);
  }

  // col-256 dots via the Q frags (fp32 reconstruct), xor-reduce over k-groups
  {
    const ushort* k6h = khb + (size_t)256 * HD + (lane >> 4) * 8;
    const ushort* k6l = klb + (size_t)256 * HD + (lane >> 4) * 8;
    float p = 0.f;
#pragma unroll
    for (int j = 0; j < 8; ++j) {
      float kf0 = bf2f(k6h[j]) + bf2f(k6l[j]);
      float kf1 = bf2f(k6h[32 + j]) + bf2f(k6l[32 + j]);
      float qf0 = bf2f((ushort)qh0[j]) + bf2f((ushort)ql0[j]);
      float qf1 = bf2f((ushort)qh1[j]) + bf2f((ushort)ql1[j]);
      p = fmaf(qf0, kf0, fmaf(qf1, kf1, p));
    }
    p += __shfl_xor(p, 16);
    p += __shfl_xor(p, 32);
    if (lane < 16) s256[wave][lane] = p;
  }

  const int g = lane >> 4, c0 = lane & 15;

  // col-256 logits (uniform within 16-lane group)
  float lg6[4];
#pragma unroll
  for (int r = 0; r < 4; ++r) {
    int gi = tile * 64 + 16 * wave + 4 * g + r;
    float d6 = s256[wave][4 * g + r];
    float bz = 0.f;
    if (gi >= 1) {
      int dx = ((gi - 1) & 15) - 15;
      int dy = ((gi - 1) >> 4) - 15;
      float rz = (cz_s[gi - 1] - cz_s[255]) * 16.0f;
      int iz = (int)rintf(rz); iz = max(-16, min(16, iz));
      bz = txd[dx + 15] + tyd[dy + 15] + tzt[iz + 16];
    }
    lg6[r] = scale * d6 + bz;
  }

  // bias -> logits in place
#pragma unroll
  for (int jt = 0; jt < 16; ++jt) {
    int col = jt * 16 + c0;
#pragma unroll
    for (int r = 0; r < 4; ++r) {
      int gi = tile * 64 + 16 * wave + 4 * g + r;
      float lv = scale * acc[jt][r];
      if (col >= 1 && gi >= 1) {
        int dx = ((gi - 1) & 15) - ((col - 1) & 15);
        int dy = ((gi - 1) >> 4) - ((col - 1) >> 4);
        float rz = (cz_s[gi - 1] - cz_s[col - 1]) * 16.0f;
        int iz = (int)rintf(rz); iz = max(-16, min(16, iz));
        lv += txd[dx + 15] + tyd[dy + 15] + tzt[iz + 16];
      }
      acc[jt][r] = lv;
    }
  }

  // softmax per row (rows live in (g,r); reduce across low-4 lane bits)
  float* Pb_ = P + (size_t)b * L_TOK * L_TOK;
#pragma unroll
  for (int r = 0; r < 4; ++r) {
    int gi = tile * 64 + 16 * wave + 4 * g + r;
    float m = acc[0][r];
#pragma unroll
    for (int jt = 1; jt < 16; ++jt) m = fmaxf(m, acc[jt][r]);
#pragma unroll
    for (int o = 1; o < 16; o <<= 1) m = fmaxf(m, __shfl_xor(m, o));
    m = fmaxf(m, lg6[r]);
    float s = 0.f;
#pragma unroll
    for (int jt = 0; jt < 16; ++jt) {
      float e = __expf(acc[jt][r] - m);
      acc[jt][r] = e;
      s += e;
    }
#pragma unroll
    for (int o = 1; o < 16; o <<= 1) s += __shfl_xor(s, o);
    float e6 = __expf(lg6[r] - m);
    float inv = 1.0f / (s + e6);
    float* Prow = Pb_ + (size_t)gi * L_TOK;
#pragma unroll
    for (int jt = 0; jt < 16; ++jt)
      Prow[jt * 16 + c0] = acc[jt][r] * inv;
    if (c0 == 0) Prow[256] = e6 * inv;
  }
}

// ---------------- row 256: plain VALU dot + softmax ----------------
__global__ __launch_bounds__(256)
void attn_row256(const ushort* __restrict__ qhi, const ushort* __restrict__ qlo,
                 const ushort* __restrict__ khi, const ushort* __restrict__ klo,
                 const float* __restrict__ depth, const float* __restrict__ rpe,
                 const float* __restrict__ lscale, float* __restrict__ P) {
  __shared__ float qs[HD];
  __shared__ float cz_s[HW];
  __shared__ float txd[32], tyd[32], tzt[36];
  __shared__ float red_s[16];
  __shared__ float lg6_sh;

  const int b = blockIdx.x;
  const int n = b / N_H, h = b - n * N_H;
  const int t = threadIdx.x;
  const int lane = t & 63, wave = t >> 6;

  float dval = depth[n * HW + t];
  float mn = dval, mx = dval;
#pragma unroll
  for (int o = 32; o > 0; o >>= 1) {
    mn = fminf(mn, __shfl_down(mn, o));
    mx = fmaxf(mx, __shfl_down(mx, o));
  }
  if (lane == 0) { red_s[wave] = mn; red_s[8 + wave] = mx; }
  __syncthreads();
  float zmin = fminf(fminf(red_s[0], red_s[1]), fminf(red_s[2], red_s[3]));
  float zmax = fmaxf(fmaxf(red_s[8], red_s[9]), fmaxf(red_s[10], red_s[11]));
  float den = zmax - zmin + 1e-8f;
  cz_s[t] = (dval - zmin) / den;
  if (t < 31) {
    int d = t - 15;
    int ix = (int)rintf((float)d * (16.0f / 15.0f));
    ix = max(-16, min(16, ix));
    txd[t] = rpe[(ix + 16) * N_H + h];
    tyd[t] = rpe[(RPE_NUM + ix + 16) * N_H + h];
  }
  if (t < RPE_NUM) tzt[t] = rpe[(2 * RPE_NUM + t) * N_H + h];
  const float scale = expf(fminf(lscale[h], LOGIT_MAX));

  const size_t q6 = ((size_t)b * L_TOK + 256) * HD;
  if (t < HD) qs[t] = bf2f(qhi[q6 + t]) + bf2f(qlo[q6 + t]);
  __syncthreads();

  // key j = t
  const ushort* krh = khi + ((size_t)b * L_TOK + t) * HD;
  const ushort* krl = klo + ((size_t)b * L_TOK + t) * HD;
  float dot = 0.f;
#pragma unroll
  for (int c = 0; c < HD; c += 8) {
    ushort4 hv0 = *(const ushort4*)(krh + c);
    ushort4 hv1 = *(const ushort4*)(krh + c + 4);
    ushort4 lv0 = *(const ushort4*)(krl + c);
    ushort4 lv1 = *(const ushort4*)(krl + c + 4);
    dot = fmaf(bf2f(hv0.x) + bf2f(lv0.x), qs[c + 0], dot);
    dot = fmaf(bf2f(hv0.y) + bf2f(lv0.y), qs[c + 1], dot);
    dot = fmaf(bf2f(hv0.z) + bf2f(lv0.z), qs[c + 2], dot);
    dot = fmaf(bf2f(hv0.w) + bf2f(lv0.w), qs[c + 3], dot);
    dot = fmaf(bf2f(hv1.x) + bf2f(lv1.x), qs[c + 4], dot);
    dot = fmaf(bf2f(hv1.y) + bf2f(lv1.y), qs[c + 5], dot);
    dot = fmaf(bf2f(hv1.z) + bf2f(lv1.z), qs[c + 6], dot);
    dot = fmaf(bf2f(hv1.w) + bf2f(lv1.w), qs[c + 7], dot);
  }

  float lg;
  {
    float bsum = 0.f;
    if (t >= 1) {
      int dx = 15 - ((t - 1) & 15);
      int dy = 15 - ((t - 1) >> 4);
      float rz = (cz_s[255] - cz_s[t - 1]) * 16.0f;
      int iz = (int)rintf(rz); iz = max(-16, min(16, iz));
      bsum = txd[dx + 15] + tyd[dy + 15] + tzt[iz + 16];
    }
    lg = scale * dot + bsum;
  }

  // key 256 by wave 0
  if (wave == 0) {
    const ushort* k6h = khi + q6;
    const ushort* k6l = klo + q6;
    float pp = (bf2f(k6h[lane]) + bf2f(k6l[lane])) * qs[lane];
#pragma unroll
    for (int o = 32; o > 0; o >>= 1) pp += __shfl_down(pp, o);
    if (lane == 0) {
      // bias(256,256): dx=dy=0, rz=0 -> iz=0
      float bz = txd[15] + tyd[15] + tzt[16];
      lg6_sh = scale * pp + bz;
    }
  }

  // block softmax over 257
  float m = lg;
#pragma unroll
  for (int o = 32; o > 0; o >>= 1) m = fmaxf(m, __shfl_down(m, o));
  if (lane == 0) red_s[wave] = m;
  __syncthreads();
  float M = fmaxf(fmaxf(red_s[0], red_s[1]), fmaxf(red_s[2], red_s[3]));
  M = fmaxf(M, lg6_sh);
  float e = __expf(lg - M);
  float s = e;
#pragma unroll
  for (int o = 32; o > 0; o >>= 1) s += __shfl_down(s, o);
  if (lane == 0) red_s[8 + wave] = s;
  __syncthreads();
  float e6 = __expf(lg6_sh - M);
  float S = (red_s[8] + red_s[9]) + (red_s[10] + red_s[11]) + e6;
  float inv = 1.0f / S;
  float* Prow = P + (size_t)b * L_TOK * L_TOK + (size_t)256 * L_TOK;
  Prow[t] = e * inv;
  if (t == 0) Prow[256] = e6 * inv;
}

// ---------------- PV via MFMA -> bf16 hi/lo A-matrix for out-proj ----------------
__global__ __launch_bounds__(256)
void pv_mfma(const float* __restrict__ P, const ushort* __restrict__ vthi,
             const ushort* __restrict__ vtlo, const float* __restrict__ v,
             ushort* __restrict__ ahi, ushort* __restrict__ alo) {
  const int b = blockIdx.y;
  const int n = b / N_H, h = b - n * N_H;
  const int t = threadIdx.x;
  const int lane = t & 63, wave = t >> 6;
  const int rbase = blockIdx.x * 128 + wave * 32;   // 32 rows per wave
  const float* Pb = P + (size_t)b * L_TOK * L_TOK;
  const ushort* vh = vthi + (size_t)b * HD * VT_STRIDE;
  const ushort* vl = vtlo + (size_t)b * HD * VT_STRIDE;

  const int fm = lane & 15, fk = (lane >> 4) * 8;
  f32x4 acc[2][4] = {};

  for (int k0 = 0; k0 < 256; k0 += 32) {
    short8 ah[2], al[2], bh[4], bl[4];
#pragma unroll
    for (int i = 0; i < 2; ++i) {
      const float* pr = Pb + (size_t)(rbase + i * 16 + fm) * L_TOK + k0 + fk;
#pragma unroll
      for (int j = 0; j < 8; ++j) {
        float pv_ = pr[j];
        ushort hh = f2bf_rn(pv_);
        ah[i][j] = (short)hh;
        al[i][j] = (short)f2bf_rn(pv_ - bf2f(hh));
      }
    }
#pragma unroll
    for (int j = 0; j < 4; ++j) {
      const ushort* bp = vh + (size_t)(j * 16 + fm) * VT_STRIDE + k0 + fk;
      const ushort* bq = vl + (size_t)(j * 16 + fm) * VT_STRIDE + k0 + fk;
      bh[j] = *(const short8*)bp;
      bl[j] = *(const short8*)bq;
    }
#pragma unroll
    for (int i = 0; i < 2; ++i)
#pragma unroll
      for (int j = 0; j < 4; ++j) {
        acc[i][j] = __builtin_amdgcn_mfma_f32_16x16x32_bf16(ah[i], bh[j], acc[i][j], 0, 0, 0);
        acc[i][j] = __builtin_amdgcn_mfma_f32_16x16x32_bf16(ah[i], bl[j], acc[i][j], 0, 0, 0);
        acc[i][j] = __builtin_amdgcn_mfma_f32_16x16x32_bf16(al[i], bh[j], acc[i][j], 0, 0, 0);
        acc[i][j] = __builtin_amdgcn_mfma_f32_16x16x32_bf16(al[i], bl[j], acc[i][j], 0, 0, 0);
      }
  }

  // k = 256 tail, exact fp32 (v is [b][l][64])
  const int g = lane >> 4;
  float v6[4];
#pragma unroll
  for (int j = 0; j < 4; ++j)
    v6[j] = v[((size_t)b * L_TOK + 256) * HD + j * 16 + fm];
#pragma unroll
  for (int i = 0; i < 2; ++i)
#pragma unroll
    for (int r = 0; r < 4; ++r) {
      int row = rbase + i * 16 + g * 4 + r;
      float p6 = Pb[(size_t)row * L_TOK + 256];
#pragma unroll
      for (int j = 0; j < 4; ++j) acc[i][j][r] += p6 * v6[j];
    }

  // write A[row=l*32+n][col=h*64+d] as bf16 hi/lo
#pragma unroll
  for (int i = 0; i < 2; ++i)
#pragma unroll
    for (int r = 0; r < 4; ++r) {
      int row = rbase + i * 16 + g * 4 + r;
      size_t o = ((size_t)row * N_B + n) * C_DIM + h * HD;
#pragma unroll
      for (int j = 0; j < 4; ++j) {
        float val = acc[i][j][r];
        ushort hv = f2bf_rn(val);
        ahi[o + j * 16 + fm] = hv;
        alo[o + j * 16 + fm] = f2bf_rn(val - bf2f(hv));
      }
    }

  // row 256 (exact fp32), done once per b by block.x==0
  if (blockIdx.x == 0 && t < HD) {
    const float* Prow = Pb + (size_t)256 * L_TOK;
    const float* vb = v + (size_t)b * L_TOK * HD;
    float sum = 0.f;
    for (int k = 0; k < L_TOK; ++k)
      sum = fmaf(Prow[k], vb[(size_t)k * HD + t], sum);
    size_t o = ((size_t)256 * N_B + n) * C_DIM + h * HD + t;
    ushort hv = f2bf_rn(sum);
    ahi[o] = hv;
    alo[o] = f2bf_rn(sum - bf2f(hv));
  }
}

extern "C" void kernel_launch(void* const* d_in, const int* in_sizes, int n_in,
                              void* d_out, int out_size, void* d_ws, size_t ws_size,
                              hipStream_t stream) {
  const float* x      = (const float*)d_in[0];
  const float* depth  = (const float*)d_in[1];
  const float* w_in   = (const float*)d_in[2];
  const float* b_in   = (const float*)d_in[3];
  const float* w_out  = (const float*)d_in[4];
  const float* b_out  = (const float*)d_in[5];
  const float* rpe    = (const float*)d_in[6];
  const float* lscale = (const float*)d_in[7];
  float* out = (float*)d_out;
  float* ws = (float*)d_ws;

  // layout (float units). Lifetimes:
  //   xhi/xlo [0..6.3M)       : cvt(x) -> QKV gemm; dead after -> reused as ahi/alo by pv
  //   vthi/vtlo [6.3M..12.8M) : vt_make -> pv; dead after
  //   v [18.9M..25.3M)        : QKV gemm -> vt_make, pv
  //   qhi..klo [25.3M..37.9M) : QKV gemm -> attn
  //   w splits [37.9M..40.3M) : persistent
  ushort* xhi  = (ushort*)ws;                   // 6,316,032 ushorts
  ushort* xlo  = xhi + 6316032;
  ushort* vthi = (ushort*)(ws + 6316032);       // 6,488,064 ushorts each
  ushort* vtlo = vthi + 6488064;
  float*  v    = ws + 18948096;                 // 6,316,032 floats
  ushort* qhi  = (ushort*)(ws + 25264128);      // 6,316,032 ushorts each
  ushort* qlo  = qhi + 6316032;
  ushort* khi  = qlo + 6316032;
  ushort* klo  = khi + 6316032;
  ushort* wihi = (ushort*)(ws + 37896192);      // 1,769,472 each
  ushort* wilo = wihi + 1769472;
  ushort* wohi = wilo + 1769472;                // 589,824 each
  ushort* wolo = wohi + 589824;
  ushort* ahi  = xhi;                           // overlay: x splits dead after QKV gemm
  ushort* alo  = xlo;
  float* Pout = out + 6316032;

  cvt_split<<<6168, 256, 0, stream>>>(x, xhi, xlo, 6316032);
  cvt_split<<<1728, 256, 0, stream>>>(w_in, wihi, wilo, 1769472);
  cvt_split<<<576, 256, 0, stream>>>(w_out, wohi, wolo, 589824);

  gemm_qkv_fused<<<MT_Q * NT_Q, 256, 0, stream>>>(xhi, xlo, wihi, wilo, b_in,
                                                  qhi, qlo, khi, klo, v);
  vt_make<<<BH, 256, 0, stream>>>(v, vthi, vtlo);
  attn_mfma<<<dim3(4, BH), 256, 0, stream>>>(qhi, qlo, khi, klo, depth, rpe, lscale, Pout);
  attn_row256<<<BH, 256, 0, stream>>>(qhi, qlo, khi, klo, depth, rpe, lscale, Pout);
  pv_mfma<<<dim3(2, BH), 256, 0, stream>>>(Pout, vthi, vtlo, v, ahi, alo);

  gemm_out_n64<<<MT_Q * NT_O, 256, 0, stream>>>(ahi, alo, wohi, wolo, b_out, out);
}

// Round 4
// 454.328 us; speedup vs baseline: 1.2952x; 1.0876x over previous
//
#include <hip/hip_runtime.h>
#include <math.h>

#define L_TOK 257
#define N_B 32
#define C_DIM 768
#define N_H 12
#define HD 64
#define BH (N_B * N_H)          /* 384 */
#define M_TOK (L_TOK * N_B)     /* 8224 */
#define HW 256
#define RPE_NUM 33
#define LOGIT_MAX 4.6051701859880913680f
#define VT_STRIDE 264
#define MT_Q 65                 /* gemm M-tiles (128-row) */
#define NT_Q 18                 /* QKV gemm N-tiles (128-col) */
#define NT_O 6                  /* out-proj N-tiles (128-col) */
#define NTK 24                  /* K-steps (768/32) */

typedef unsigned short ushort;
typedef unsigned int uint;
typedef __attribute__((ext_vector_type(8))) short short8;
typedef __attribute__((ext_vector_type(4))) float f32x4;

__device__ __forceinline__ ushort f2bf_rn(float f) {
  uint u = __float_as_uint(f);
  uint r = (u + 0x7FFF + ((u >> 16) & 1)) >> 16;
  return (ushort)r;
}
__device__ __forceinline__ float bf2f(ushort h) {
  return __uint_as_float(((uint)h) << 16);
}

__device__ __forceinline__ int xcd_swz(int wid, int nwg) {
  int q = nwg >> 3, r = nwg & 7;
  int xcd = wid & 7, pos = wid >> 3;
  int base = (xcd < r) ? xcd * (q + 1) : r * (q + 1) + (xcd - r) * q;
  return base + pos;
}

// 2-D supertile map: contiguous wid-chunks cover 8-m-tile x NT-n-tile rects.
__device__ __forceinline__ void tile_map(int bid, int MT, int NT, int nwg,
                                         int& m0, int& nt) {
  int wid = xcd_swz(bid, nwg);
  int per = 8 * NT;
  int s = wid / per;
  int rem = wid - s * per;
  int msz = MT - s * 8; if (msz > 8) msz = 8;
  int mi = rem % msz, ni = rem / msz;
  m0 = (s * 8 + mi) * 128;
  nt = ni;
}

// ---------------- fp32 -> bf16 hi/lo split ----------------
__global__ __launch_bounds__(256)
void cvt_split(const float* __restrict__ src, ushort* __restrict__ hi,
               ushort* __restrict__ lo, int n) {
  int i = (blockIdx.x * 256 + threadIdx.x) * 4;
  if (i + 3 >= n + 3) return;
  if (i + 3 < n) {
    float4 v = *(const float4*)(src + i);
    ushort h0 = f2bf_rn(v.x), h1 = f2bf_rn(v.y), h2 = f2bf_rn(v.z), h3 = f2bf_rn(v.w);
    ushort l0 = f2bf_rn(v.x - bf2f(h0)), l1 = f2bf_rn(v.y - bf2f(h1));
    ushort l2 = f2bf_rn(v.z - bf2f(h2)), l3 = f2bf_rn(v.w - bf2f(h3));
    *(ushort4*)(hi + i) = make_ushort4(h0, h1, h2, h3);
    *(ushort4*)(lo + i) = make_ushort4(l0, l1, l2, l3);
  } else {
    for (int k = i; k < n; ++k) {
      float vv = src[k];
      ushort h = f2bf_rn(vv);
      hi[k] = h; lo[k] = f2bf_rn(vv - bf2f(h));
    }
  }
}

// ---------------- counted-vmcnt 3-phase split-3 GEMM core ----------------
// BM=BN=128, BK=32, 4 waves, dbuf LDS 64KB. Phases per K-step:
//   P1: wait own {Ah,Bh}(vmcnt 4) -> barrier -> ds ah,bh -> issue next Ah,Bh -> 16 mfma hh
//   P2: wait own {Al}  (vmcnt 6) -> barrier -> ds al     -> issue next Al   -> 16 mfma lh
//   P3: wait own {Bl}  (vmcnt 6) -> barrier -> ds bl     -> issue next Bl   -> 16 mfma hl
// T2 swizzle: LDS dest linear (global_load_lds), global SOURCE col pre-swizzled
// by slot^((row>>1)&3); fragment reads apply the same XOR (involution).
__device__ __forceinline__ void stage_pair(const ushort* g0, const ushort* g1,
                                           ushort* l, uint so) {
  __builtin_amdgcn_global_load_lds(
      (const __attribute__((address_space(1))) void*)g0,
      (__attribute__((address_space(3))) void*)((char*)l + so), 16, 0, 0);
  __builtin_amdgcn_global_load_lds(
      (const __attribute__((address_space(1))) void*)g1,
      (__attribute__((address_space(3))) void*)((char*)l + so + 4096), 16, 0, 0);
}

#define PH_WAIT(N)                                        \
  asm volatile("s_waitcnt vmcnt(" #N ")" ::: "memory");   \
  __builtin_amdgcn_s_barrier();                           \
  __builtin_amdgcn_sched_barrier(0);

#define PH_LGKM()                                         \
  asm volatile("s_waitcnt lgkmcnt(0)" ::: "memory");      \
  __builtin_amdgcn_sched_barrier(0);

__device__ __forceinline__ void gemm3_core(
    const ushort* __restrict__ Ahi, const ushort* __restrict__ Alo,
    const ushort* __restrict__ Bhi, const ushort* __restrict__ Blo,
    int m0, int n0, ushort* lds, f32x4 (&acc)[4][4]) {
  const int K = C_DIM, M = M_TOK;
  const int t = threadIdx.x;
  const int wave = t >> 6, lane = t & 63;
  const int wm = (wave & 1) * 64, wn = (wave >> 1) * 64;
  const int frm = lane & 15, fs = lane >> 4;
  const int sx = (fs ^ ((frm >> 1) & 3)) * 8;   // read-side swizzled slot

  // staging geometry: thread t stages local row ar (and ar+64), LDS slot t&3;
  // source col swizzled so LDS[r][slot] = global[r][8*(slot^((r>>1)&3))]
  const int ar = t >> 2;
  const int acs = ((t & 3) ^ ((ar >> 1) & 3)) * 8;
  const uint so = (uint)(t & 192) * 16;         // wave-uniform byte base

  int rA0 = m0 + ar;      if (rA0 > M - 1) rA0 = M - 1;
  int rA1 = m0 + 64 + ar; if (rA1 > M - 1) rA1 = M - 1;
  const size_t gA0 = (size_t)rA0 * K + acs;
  const size_t gA1 = (size_t)rA1 * K + acs;
  const size_t gB0 = (size_t)(n0 + ar) * K + acs;
  const size_t gB1 = (size_t)(n0 + 64 + ar) * K + acs;

  // prologue: tile 0 -> buf 0, issue order Ah,Bh,Al,Bl (2 each)
  stage_pair(Ahi + gA0, Ahi + gA1, lds, so);
  stage_pair(Bhi + gB0, Bhi + gB1, lds + 4096, so);
  stage_pair(Alo + gA0, Alo + gA1, lds + 8192, so);
  stage_pair(Blo + gB0, Blo + gB1, lds + 12288, so);

  short8 ah[4], bh[4], al[4], bl[4];

#pragma unroll 2
  for (int kt = 0; kt < NTK - 1; ++kt) {
    const int curo = (kt & 1) << 14;
    const int nxo = curo ^ 16384;
    const int kn = (kt + 1) * 32;
    // ---- P1: hh ----
    PH_WAIT(4)
#pragma unroll
    for (int i = 0; i < 4; ++i) {
      ah[i] = *(const short8*)(lds + curo + (wm + i * 16 + frm) * 32 + sx);
      bh[i] = *(const short8*)(lds + curo + 4096 + (wn + i * 16 + frm) * 32 + sx);
    }
    stage_pair(Ahi + gA0 + kn, Ahi + gA1 + kn, lds + nxo, so);
    stage_pair(Bhi + gB0 + kn, Bhi + gB1 + kn, lds + nxo + 4096, so);
    PH_LGKM()
    __builtin_amdgcn_s_setprio(1);
#pragma unroll
    for (int i = 0; i < 4; ++i)
#pragma unroll
      for (int j = 0; j < 4; ++j)
        acc[i][j] = __builtin_amdgcn_mfma_f32_16x16x32_bf16(ah[i], bh[j], acc[i][j], 0, 0, 0);
    __builtin_amdgcn_s_setprio(0);
    __builtin_amdgcn_sched_barrier(0);
    // ---- P2: lh ----
    PH_WAIT(6)
#pragma unroll
    for (int i = 0; i < 4; ++i)
      al[i] = *(const short8*)(lds + curo + 8192 + (wm + i * 16 + frm) * 32 + sx);
    stage_pair(Alo + gA0 + kn, Alo + gA1 + kn, lds + nxo + 8192, so);
    PH_LGKM()
    __builtin_amdgcn_s_setprio(1);
#pragma unroll
    for (int i = 0; i < 4; ++i)
#pragma unroll
      for (int j = 0; j < 4; ++j)
        acc[i][j] = __builtin_amdgcn_mfma_f32_16x16x32_bf16(al[i], bh[j], acc[i][j], 0, 0, 0);
    __builtin_amdgcn_s_setprio(0);
    __builtin_amdgcn_sched_barrier(0);
    // ---- P3: hl ----
    PH_WAIT(6)
#pragma unroll
    for (int i = 0; i < 4; ++i)
      bl[i] = *(const short8*)(lds + curo + 12288 + (wn + i * 16 + frm) * 32 + sx);
    stage_pair(Blo + gB0 + kn, Blo + gB1 + kn, lds + nxo + 12288, so);
    PH_LGKM()
    __builtin_amdgcn_s_setprio(1);
#pragma unroll
    for (int i = 0; i < 4; ++i)
#pragma unroll
      for (int j = 0; j < 4; ++j)
        acc[i][j] = __builtin_amdgcn_mfma_f32_16x16x32_bf16(ah[i], bl[j], acc[i][j], 0, 0, 0);
    __builtin_amdgcn_s_setprio(0);
    __builtin_amdgcn_sched_barrier(0);
  }
  // ---- final K-step: no issues, drain counts 4/2/0 ----
  {
    const int curo = ((NTK - 1) & 1) << 14;
    PH_WAIT(4)
#pragma unroll
    for (int i = 0; i < 4; ++i) {
      ah[i] = *(const short8*)(lds + curo + (wm + i * 16 + frm) * 32 + sx);
      bh[i] = *(const short8*)(lds + curo + 4096 + (wn + i * 16 + frm) * 32 + sx);
    }
    PH_LGKM()
#pragma unroll
    for (int i = 0; i < 4; ++i)
#pragma unroll
      for (int j = 0; j < 4; ++j)
        acc[i][j] = __builtin_amdgcn_mfma_f32_16x16x32_bf16(ah[i], bh[j], acc[i][j], 0, 0, 0);
    __builtin_amdgcn_sched_barrier(0);
    PH_WAIT(2)
#pragma unroll
    for (int i = 0; i < 4; ++i)
      al[i] = *(const short8*)(lds + curo + 8192 + (wm + i * 16 + frm) * 32 + sx);
    PH_LGKM()
#pragma unroll
    for (int i = 0; i < 4; ++i)
#pragma unroll
      for (int j = 0; j < 4; ++j)
        acc[i][j] = __builtin_amdgcn_mfma_f32_16x16x32_bf16(al[i], bh[j], acc[i][j], 0, 0, 0);
    __builtin_amdgcn_sched_barrier(0);
    PH_WAIT(0)
#pragma unroll
    for (int i = 0; i < 4; ++i)
      bl[i] = *(const short8*)(lds + curo + 12288 + (wn + i * 16 + frm) * 32 + sx);
    PH_LGKM()
#pragma unroll
    for (int i = 0; i < 4; ++i)
#pragma unroll
      for (int j = 0; j < 4; ++j)
        acc[i][j] = __builtin_amdgcn_mfma_f32_16x16x32_bf16(ah[i], bl[j], acc[i][j], 0, 0, 0);
    __builtin_amdgcn_sched_barrier(0);
  }
}

// ---------------- fused QKV GEMM (new core + norm epilogue) ----------------
__global__ __launch_bounds__(256)
void gemm_qkv_fused(const ushort* __restrict__ Ahi, const ushort* __restrict__ Alo,
                    const ushort* __restrict__ Bhi, const ushort* __restrict__ Blo,
                    const float* __restrict__ bias,
                    ushort* __restrict__ qhi, ushort* __restrict__ qlo,
                    ushort* __restrict__ khi, ushort* __restrict__ klo,
                    float* __restrict__ vout) {
  __shared__ __align__(16) ushort lds[32768];   // 64 KB dbuf
  int m0, nt;
  tile_map(blockIdx.x, MT_Q, NT_Q, MT_Q * NT_Q, m0, nt);
  const int n0 = nt * 128;
  f32x4 acc[4][4] = {};
  gemm3_core(Ahi, Alo, Bhi, Blo, m0, n0, lds, acc);

  const int M = M_TOK;
  const int t = threadIdx.x;
  const int wave = t >> 6, lane = t & 63;
  const int wm = (wave & 1) * 64, wn = (wave >> 1) * 64;
  const int c0 = lane & 15, g = lane >> 4;
  const int colBase = n0 + wn;                 // multiple of 64 -> one head
  const int sect = colBase / C_DIM;            // 0:q 1:k 2:v
  const int hh = (colBase - sect * C_DIM) >> 6;
  float bv[4];
#pragma unroll
  for (int j = 0; j < 4; ++j) bv[j] = bias[colBase + j * 16 + c0];

#pragma unroll
  for (int i = 0; i < 4; ++i) {
#pragma unroll
    for (int r = 0; r < 4; ++r) {
      const int row = m0 + wm + i * 16 + g * 4 + r;
      float lv[4];
#pragma unroll
      for (int j = 0; j < 4; ++j) lv[j] = acc[i][j][r] + bv[j];
      if (sect == 2) {
        if (row < M) {
          int l = row >> 5, n = row & 31;
          size_t ob = ((size_t)((n * N_H + hh) * L_TOK + l)) * HD;
#pragma unroll
          for (int j = 0; j < 4; ++j) vout[ob + j * 16 + c0] = lv[j];
        }
      } else {
        float ss = lv[0] * lv[0] + lv[1] * lv[1] + lv[2] * lv[2] + lv[3] * lv[3];
        ss += __shfl_xor(ss, 1);
        ss += __shfl_xor(ss, 2);
        ss += __shfl_xor(ss, 4);
        ss += __shfl_xor(ss, 8);
        float inv = 1.0f / fmaxf(sqrtf(ss), 1e-12f);
        if (row < M) {
          int l = row >> 5, n = row & 31;
          size_t ob = ((size_t)((n * N_H + hh) * L_TOK + l)) * HD;
          ushort* dh = sect ? khi : qhi;
          ushort* dl = sect ? klo : qlo;
#pragma unroll
          for (int j = 0; j < 4; ++j) {
            float val = lv[j] * inv;
            ushort hv = f2bf_rn(val);
            dh[ob + j * 16 + c0] = hv;
            dl[ob + j * 16 + c0] = f2bf_rn(val - bf2f(hv));
          }
        }
      }
    }
  }
}

// ---------------- out-proj GEMM (new core + bias epilogue) ----------------
__global__ __launch_bounds__(256)
void gemm_out(const ushort* __restrict__ Ahi, const ushort* __restrict__ Alo,
              const ushort* __restrict__ Bhi, const ushort* __restrict__ Blo,
              const float* __restrict__ bias, float* __restrict__ Cout) {
  __shared__ __align__(16) ushort lds[32768];
  int m0, nt;
  tile_map(blockIdx.x, MT_Q, NT_O, MT_Q * NT_O, m0, nt);
  const int n0 = nt * 128;
  f32x4 acc[4][4] = {};
  gemm3_core(Ahi, Alo, Bhi, Blo, m0, n0, lds, acc);

  const int M = M_TOK, Nn = C_DIM;
  const int t = threadIdx.x;
  const int wave = t >> 6, lane = t & 63;
  const int wm = (wave & 1) * 64, wn = (wave >> 1) * 64;
  const int ecol = lane & 15;
#pragma unroll
  for (int j = 0; j < 4; ++j) {
    int col = n0 + wn + j * 16 + ecol;
    float bv = bias[col];
#pragma unroll
    for (int i = 0; i < 4; ++i) {
      int rbase = m0 + wm + i * 16 + (lane >> 4) * 4;
#pragma unroll
      for (int r = 0; r < 4; ++r) {
        int row = rbase + r;
        if (row < M) Cout[(size_t)row * Nn + col] = acc[i][j][r] + bv;
      }
    }
  }
}

// ---------------- V transpose ----------------
__global__ __launch_bounds__(256)
void vt_make(const float* __restrict__ v, ushort* __restrict__ vthi,
             ushort* __restrict__ vtlo) {
  __shared__ float sT[64][65];
  const int b = blockIdx.x;
  const int t = threadIdx.x;
  const float* vb = v + (size_t)b * L_TOK * HD;
  ushort* vh = vthi + (size_t)b * HD * VT_STRIDE;
  ushort* vl = vtlo + (size_t)b * HD * VT_STRIDE;
  for (int k0 = 0; k0 < 256; k0 += 64) {
#pragma unroll
    for (int p = 0; p < 16; ++p) {
      int idx = p * 256 + t;
      int k = idx >> 6, d = idx & 63;
      sT[d][k] = vb[(size_t)(k0 + k) * HD + d];
    }
    __syncthreads();
#pragma unroll
    for (int p = 0; p < 16; ++p) {
      int idx = p * 256 + t;
      int d = idx >> 6, k = idx & 63;
      float val = sT[d][k];
      ushort h = f2bf_rn(val);
      vh[(size_t)d * VT_STRIDE + k0 + k] = h;
      vl[(size_t)d * VT_STRIDE + k0 + k] = f2bf_rn(val - bf2f(h));
    }
    __syncthreads();
  }
  if (t < HD) {
    float val = vb[(size_t)256 * HD + t];
    ushort h = f2bf_rn(val);
    vh[(size_t)t * VT_STRIDE + 256] = h;
    vl[(size_t)t * VT_STRIDE + 256] = f2bf_rn(val - bf2f(h));
  }
}

// ---------------- MFMA attention: rows 0..255, softmax -> P ----------------
__global__ __launch_bounds__(256)
void attn_mfma(const ushort* __restrict__ qhi, const ushort* __restrict__ qlo,
               const ushort* __restrict__ khi, const ushort* __restrict__ klo,
               const float* __restrict__ depth, const float* __restrict__ rpe,
               const float* __restrict__ lscale, float* __restrict__ P) {
  __shared__ __align__(16) ushort sKh[256 * 72];
  __shared__ __align__(16) ushort sKl[256 * 72];
  __shared__ float cz_s[HW];
  __shared__ float txd[32], tyd[32], tzt[36];
  __shared__ float red_s[16];
  __shared__ float s256[4][16];

  const int tile = blockIdx.x;
  const int b = blockIdx.y;
  const int n = b / N_H, h = b - n * N_H;
  const int t = threadIdx.x;
  const int lane = t & 63, wave = t >> 6;

  float dval = depth[n * HW + t];
  float mn = dval, mx = dval;
#pragma unroll
  for (int o = 32; o > 0; o >>= 1) {
    mn = fminf(mn, __shfl_down(mn, o));
    mx = fmaxf(mx, __shfl_down(mx, o));
  }
  if (lane == 0) { red_s[wave] = mn; red_s[8 + wave] = mx; }
  __syncthreads();
  float zmin = fminf(fminf(red_s[0], red_s[1]), fminf(red_s[2], red_s[3]));
  float zmax = fmaxf(fmaxf(red_s[8], red_s[9]), fmaxf(red_s[10], red_s[11]));
  float den = zmax - zmin + 1e-8f;
  cz_s[t] = (dval - zmin) / den;
  if (t < 31) {
    int d = t - 15;
    int ix = (int)rintf((float)d * (16.0f / 15.0f));
    ix = max(-16, min(16, ix));
    txd[t] = rpe[(ix + 16) * N_H + h];
    tyd[t] = rpe[(RPE_NUM + ix + 16) * N_H + h];
  }
  if (t < RPE_NUM) tzt[t] = rpe[(2 * RPE_NUM + t) * N_H + h];
  const float scale = expf(fminf(lscale[h], LOGIT_MAX));

  const ushort* khb = khi + (size_t)b * L_TOK * HD;
  const ushort* klb = klo + (size_t)b * L_TOK * HD;
#pragma unroll
  for (int it = 0; it < 8; ++it) {
    int idx = it * 256 + t;
    int j = idx >> 3, c = (idx & 7) * 8;
    *(uint4*)(sKh + j * 72 + c) = *(const uint4*)(khb + (size_t)j * HD + c);
    *(uint4*)(sKl + j * 72 + c) = *(const uint4*)(klb + (size_t)j * HD + c);
  }
  __syncthreads();

  const int qrow = tile * 64 + 16 * wave;
  const size_t qoff = ((size_t)b * L_TOK + qrow + (lane & 15)) * HD + (lane >> 4) * 8;
  short8 qh0 = *(const short8*)(qhi + qoff);
  short8 qh1 = *(const short8*)(qhi + qoff + 32);
  short8 ql0 = *(const short8*)(qlo + qoff);
  short8 ql1 = *(const short8*)(qlo + qoff + 32);

  f32x4 acc[16] = {};
#pragma unroll
  for (int jt = 0; jt < 16; ++jt) {
    const ushort* bp = sKh + (jt * 16 + (lane & 15)) * 72 + (lane >> 4) * 8;
    const ushort* bq = sKl + (jt * 16 + (lane & 15)) * 72 + (lane >> 4) * 8;
    short8 bh0 = *(const short8*)(bp);
    short8 bh1 = *(const short8*)(bp + 32);
    short8 bl0 = *(const short8*)(bq);
    short8 bl1 = *(const short8*)(bq + 32);
    acc[jt] = __builtin_amdgcn_mfma_f32_16x16x32_bf16(qh0, bh0, acc[jt], 0, 0, 0);
    acc[jt] = __builtin_amdgcn_mfma_f32_16x16x32_bf16(qh1, bh1, acc[jt], 0, 0, 0);
    acc[jt] = __builtin_amdgcn_mfma_f32_16x16x32_bf16(qh0, bl0, acc[jt], 0, 0, 0);
    acc[jt] = __builtin_amdgcn_mfma_f32_16x16x32_bf16(qh1, bl1, acc[jt], 0, 0, 0);
    acc[jt] = __builtin_amdgcn_mfma_f32_16x16x32_bf16(ql0, bh0, acc[jt], 0, 0, 0);
    acc[jt] = __builtin_amdgcn_mfma_f32_16x16x32_bf16(ql1, bh1, acc[jt], 0, 0, 0);
  }

  {
    const ushort* k6h = khb + (size_t)256 * HD + (lane >> 4) * 8;
    const ushort* k6l = klb + (size_t)256 * HD + (lane >> 4) * 8;
    float p = 0.f;
#pragma unroll
    for (int j = 0; j < 8; ++j) {
      float kf0 = bf2f(k6h[j]) + bf2f(k6l[j]);
      float kf1 = bf2f(k6h[32 + j]) + bf2f(k6l[32 + j]);
      float qf0 = bf2f((ushort)qh0[j]) + bf2f((ushort)ql0[j]);
      float qf1 = bf2f((ushort)qh1[j]) + bf2f((ushort)ql1[j]);
      p = fmaf(qf0, kf0, fmaf(qf1, kf1, p));
    }
    p += __shfl_xor(p, 16);
    p += __shfl_xor(p, 32);
    if (lane < 16) s256[wave][lane] = p;
  }

  const int g = lane >> 4, c0 = lane & 15;

  float lg6[4];
#pragma unroll
  for (int r = 0; r < 4; ++r) {
    int gi = tile * 64 + 16 * wave + 4 * g + r;
    float d6 = s256[wave][4 * g + r];
    float bz = 0.f;
    if (gi >= 1) {
      int dx = ((gi - 1) & 15) - 15;
      int dy = ((gi - 1) >> 4) - 15;
      float rz = (cz_s[gi - 1] - cz_s[255]) * 16.0f;
      int iz = (int)rintf(rz); iz = max(-16, min(16, iz));
      bz = txd[dx + 15] + tyd[dy + 15] + tzt[iz + 16];
    }
    lg6[r] = scale * d6 + bz;
  }

#pragma unroll
  for (int jt = 0; jt < 16; ++jt) {
    int col = jt * 16 + c0;
#pragma unroll
    for (int r = 0; r < 4; ++r) {
      int gi = tile * 64 + 16 * wave + 4 * g + r;
      float lv = scale * acc[jt][r];
      if (col >= 1 && gi >= 1) {
        int dx = ((gi - 1) & 15) - ((col - 1) & 15);
        int dy = ((gi - 1) >> 4) - ((col - 1) >> 4);
        float rz = (cz_s[gi - 1] - cz_s[col - 1]) * 16.0f;
        int iz = (int)rintf(rz); iz = max(-16, min(16, iz));
        lv += txd[dx + 15] + tyd[dy + 15] + tzt[iz + 16];
      }
      acc[jt][r] = lv;
    }
  }

  float* Pb_ = P + (size_t)b * L_TOK * L_TOK;
#pragma unroll
  for (int r = 0; r < 4; ++r) {
    int gi = tile * 64 + 16 * wave + 4 * g + r;
    float m = acc[0][r];
#pragma unroll
    for (int jt = 1; jt < 16; ++jt) m = fmaxf(m, acc[jt][r]);
#pragma unroll
    for (int o = 1; o < 16; o <<= 1) m = fmaxf(m, __shfl_xor(m, o));
    m = fmaxf(m, lg6[r]);
    float s = 0.f;
#pragma unroll
    for (int jt = 0; jt < 16; ++jt) {
      float e = __expf(acc[jt][r] - m);
      acc[jt][r] = e;
      s += e;
    }
#pragma unroll
    for (int o = 1; o < 16; o <<= 1) s += __shfl_xor(s, o);
    float e6 = __expf(lg6[r] - m);
    float inv = 1.0f / (s + e6);
    float* Prow = Pb_ + (size_t)gi * L_TOK;
#pragma unroll
    for (int jt = 0; jt < 16; ++jt)
      Prow[jt * 16 + c0] = acc[jt][r] * inv;
    if (c0 == 0) Prow[256] = e6 * inv;
  }
}

// ---------------- row 256 ----------------
__global__ __launch_bounds__(256)
void attn_row256(const ushort* __restrict__ qhi, const ushort* __restrict__ qlo,
                 const ushort* __restrict__ khi, const ushort* __restrict__ klo,
                 const float* __restrict__ depth, const float* __restrict__ rpe,
                 const float* __restrict__ lscale, float* __restrict__ P) {
  __shared__ float qs[HD];
  __shared__ float cz_s[HW];
  __shared__ float txd[32], tyd[32], tzt[36];
  __shared__ float red_s[16];
  __shared__ float lg6_sh;

  const int b = blockIdx.x;
  const int n = b / N_H, h = b - n * N_H;
  const int t = threadIdx.x;
  const int lane = t & 63, wave = t >> 6;

  float dval = depth[n * HW + t];
  float mn = dval, mx = dval;
#pragma unroll
  for (int o = 32; o > 0; o >>= 1) {
    mn = fminf(mn, __shfl_down(mn, o));
    mx = fmaxf(mx, __shfl_down(mx, o));
  }
  if (lane == 0) { red_s[wave] = mn; red_s[8 + wave] = mx; }
  __syncthreads();
  float zmin = fminf(fminf(red_s[0], red_s[1]), fminf(red_s[2], red_s[3]));
  float zmax = fmaxf(fmaxf(red_s[8], red_s[9]), fmaxf(red_s[10], red_s[11]));
  float den = zmax - zmin + 1e-8f;
  cz_s[t] = (dval - zmin) / den;
  if (t < 31) {
    int d = t - 15;
    int ix = (int)rintf((float)d * (16.0f / 15.0f));
    ix = max(-16, min(16, ix));
    txd[t] = rpe[(ix + 16) * N_H + h];
    tyd[t] = rpe[(RPE_NUM + ix + 16) * N_H + h];
  }
  if (t < RPE_NUM) tzt[t] = rpe[(2 * RPE_NUM + t) * N_H + h];
  const float scale = expf(fminf(lscale[h], LOGIT_MAX));

  const size_t q6 = ((size_t)b * L_TOK + 256) * HD;
  if (t < HD) qs[t] = bf2f(qhi[q6 + t]) + bf2f(qlo[q6 + t]);
  __syncthreads();

  const ushort* krh = khi + ((size_t)b * L_TOK + t) * HD;
  const ushort* krl = klo + ((size_t)b * L_TOK + t) * HD;
  float dot = 0.f;
#pragma unroll
  for (int c = 0; c < HD; c += 8) {
    ushort4 hv0 = *(const ushort4*)(krh + c);
    ushort4 hv1 = *(const ushort4*)(krh + c + 4);
    ushort4 lv0 = *(const ushort4*)(krl + c);
    ushort4 lv1 = *(const ushort4*)(krl + c + 4);
    dot = fmaf(bf2f(hv0.x) + bf2f(lv0.x), qs[c + 0], dot);
    dot = fmaf(bf2f(hv0.y) + bf2f(lv0.y), qs[c + 1], dot);
    dot = fmaf(bf2f(hv0.z) + bf2f(lv0.z), qs[c + 2], dot);
    dot = fmaf(bf2f(hv0.w) + bf2f(lv0.w), qs[c + 3], dot);
    dot = fmaf(bf2f(hv1.x) + bf2f(lv1.x), qs[c + 4], dot);
    dot = fmaf(bf2f(hv1.y) + bf2f(lv1.y), qs[c + 5], dot);
    dot = fmaf(bf2f(hv1.z) + bf2f(lv1.z), qs[c + 6], dot);
    dot = fmaf(bf2f(hv1.w) + bf2f(lv1.w), qs[c + 7], dot);
  }

  float lg;
  {
    float bsum = 0.f;
    if (t >= 1) {
      int dx = 15 - ((t - 1) & 15);
      int dy = 15 - ((t - 1) >> 4);
      float rz = (cz_s[255] - cz_s[t - 1]) * 16.0f;
      int iz = (int)rintf(rz); iz = max(-16, min(16, iz));
      bsum = txd[dx + 15] + tyd[dy + 15] + tzt[iz + 16];
    }
    lg = scale * dot + bsum;
  }

  if (wave == 0) {
    const ushort* k6h = khi + q6;
    const ushort* k6l = klo + q6;
    float pp = (bf2f(k6h[lane]) + bf2f(k6l[lane])) * qs[lane];
#pragma unroll
    for (int o = 32; o > 0; o >>= 1) pp += __shfl_down(pp, o);
    if (lane == 0) {
      float bz = txd[15] + tyd[15] + tzt[16];
      lg6_sh = scale * pp + bz;
    }
  }

  float m = lg;
#pragma unroll
  for (int o = 32; o > 0; o >>= 1) m = fmaxf(m, __shfl_down(m, o));
  if (lane == 0) red_s[wave] = m;
  __syncthreads();
  float M = fmaxf(fmaxf(red_s[0], red_s[1]), fmaxf(red_s[2], red_s[3]));
  M = fmaxf(M, lg6_sh);
  float e = __expf(lg - M);
  float s = e;
#pragma unroll
  for (int o = 32; o > 0; o >>= 1) s += __shfl_down(s, o);
  if (lane == 0) red_s[8 + wave] = s;
  __syncthreads();
  float e6 = __expf(lg6_sh - M);
  float S = (red_s[8] + red_s[9]) + (red_s[10] + red_s[11]) + e6;
  float inv = 1.0f / S;
  float* Prow = P + (size_t)b * L_TOK * L_TOK + (size_t)256 * L_TOK;
  Prow[t] = e * inv;
  if (t == 0) Prow[256] = e6 * inv;
}

// ---------------- PV via MFMA -> bf16 hi/lo A for out-proj ----------------
__global__ __launch_bounds__(256)
void pv_mfma(const float* __restrict__ P, const ushort* __restrict__ vthi,
             const ushort* __restrict__ vtlo, const float* __restrict__ v,
             ushort* __restrict__ ahi, ushort* __restrict__ alo) {
  const int b = blockIdx.y;
  const int n = b / N_H, h = b - n * N_H;
  const int t = threadIdx.x;
  const int lane = t & 63, wave = t >> 6;
  const int rbase = blockIdx.x * 128 + wave * 32;
  const float* Pb = P + (size_t)b * L_TOK * L_TOK;
  const ushort* vh = vthi + (size_t)b * HD * VT_STRIDE;
  const ushort* vl = vtlo + (size_t)b * HD * VT_STRIDE;

  const int fm = lane & 15, fk = (lane >> 4) * 8;
  f32x4 acc[2][4] = {};

  for (int k0 = 0; k0 < 256; k0 += 32) {
    short8 ah[2], al[2], bh[4], bl[4];
#pragma unroll
    for (int i = 0; i < 2; ++i) {
      const float* pr = Pb + (size_t)(rbase + i * 16 + fm) * L_TOK + k0 + fk;
#pragma unroll
      for (int j = 0; j < 8; ++j) {
        float pv_ = pr[j];
        ushort hh = f2bf_rn(pv_);
        ah[i][j] = (short)hh;
        al[i][j] = (short)f2bf_rn(pv_ - bf2f(hh));
      }
    }
#pragma unroll
    for (int j = 0; j < 4; ++j) {
      const ushort* bp = vh + (size_t)(j * 16 + fm) * VT_STRIDE + k0 + fk;
      const ushort* bq = vl + (size_t)(j * 16 + fm) * VT_STRIDE + k0 + fk;
      bh[j] = *(const short8*)bp;
      bl[j] = *(const short8*)bq;
    }
#pragma unroll
    for (int i = 0; i < 2; ++i)
#pragma unroll
      for (int j = 0; j < 4; ++j) {
        acc[i][j] = __builtin_amdgcn_mfma_f32_16x16x32_bf16(ah[i], bh[j], acc[i][j], 0, 0, 0);
        acc[i][j] = __builtin_amdgcn_mfma_f32_16x16x32_bf16(ah[i], bl[j], acc[i][j], 0, 0, 0);
        acc[i][j] = __builtin_amdgcn_mfma_f32_16x16x32_bf16(al[i], bh[j], acc[i][j], 0, 0, 0);
        acc[i][j] = __builtin_amdgcn_mfma_f32_16x16x32_bf16(al[i], bl[j], acc[i][j], 0, 0, 0);
      }
  }

  const int g = lane >> 4;
  float v6[4];
#pragma unroll
  for (int j = 0; j < 4; ++j)
    v6[j] = v[((size_t)b * L_TOK + 256) * HD + j * 16 + fm];
#pragma unroll
  for (int i = 0; i < 2; ++i)
#pragma unroll
    for (int r = 0; r < 4; ++r) {
      int row = rbase + i * 16 + g * 4 + r;
      float p6 = Pb[(size_t)row * L_TOK + 256];
#pragma unroll
      for (int j = 0; j < 4; ++j) acc[i][j][r] += p6 * v6[j];
    }

#pragma unroll
  for (int i = 0; i < 2; ++i)
#pragma unroll
    for (int r = 0; r < 4; ++r) {
      int row = rbase + i * 16 + g * 4 + r;
      size_t o = ((size_t)row * N_B + n) * C_DIM + h * HD;
#pragma unroll
      for (int j = 0; j < 4; ++j) {
        float val = acc[i][j][r];
        ushort hv = f2bf_rn(val);
        ahi[o + j * 16 + fm] = hv;
        alo[o + j * 16 + fm] = f2bf_rn(val - bf2f(hv));
      }
    }

  if (blockIdx.x == 0 && t < HD) {
    const float* Prow = Pb + (size_t)256 * L_TOK;
    const float* vb = v + (size_t)b * L_TOK * HD;
    float sum = 0.f;
    for (int k = 0; k < L_TOK; ++k)
      sum = fmaf(Prow[k], vb[(size_t)k * HD + t], sum);
    size_t o = ((size_t)256 * N_B + n) * C_DIM + h * HD + t;
    ushort hv = f2bf_rn(sum);
    ahi[o] = hv;
    alo[o] = f2bf_rn(sum - bf2f(hv));
  }
}

extern "C" void kernel_launch(void* const* d_in, const int* in_sizes, int n_in,
                              void* d_out, int out_size, void* d_ws, size_t ws_size,
                              hipStream_t stream) {
  const float* x      = (const float*)d_in[0];
  const float* depth  = (const float*)d_in[1];
  const float* w_in   = (const float*)d_in[2];
  const float* b_in   = (const float*)d_in[3];
  const float* w_out  = (const float*)d_in[4];
  const float* b_out  = (const float*)d_in[5];
  const float* rpe    = (const float*)d_in[6];
  const float* lscale = (const float*)d_in[7];
  float* out = (float*)d_out;
  float* ws = (float*)d_ws;

  ushort* xhi  = (ushort*)ws;                   // 6,316,032 ushorts
  ushort* xlo  = xhi + 6316032;
  ushort* vthi = (ushort*)(ws + 6316032);       // 6,488,064 ushorts each
  ushort* vtlo = vthi + 6488064;
  float*  v    = ws + 18948096;                 // 6,316,032 floats
  ushort* qhi  = (ushort*)(ws + 25264128);      // 6,316,032 ushorts each
  ushort* qlo  = qhi + 6316032;
  ushort* khi  = qlo + 6316032;
  ushort* klo  = khi + 6316032;
  ushort* wihi = (ushort*)(ws + 37896192);      // 1,769,472 each
  ushort* wilo = wihi + 1769472;
  ushort* wohi = wilo + 1769472;                // 589,824 each
  ushort* wolo = wohi + 589824;
  ushort* ahi  = xhi;                           // overlay: x splits dead after QKV gemm
  ushort* alo  = xlo;
  float* Pout = out + 6316032;

  cvt_split<<<6168, 256, 0, stream>>>(x, xhi, xlo, 6316032);
  cvt_split<<<1728, 256, 0, stream>>>(w_in, wihi, wilo, 1769472);
  cvt_split<<<576, 256, 0, stream>>>(w_out, wohi, wolo, 589824);

  gemm_qkv_fused<<<MT_Q * NT_Q, 256, 0, stream>>>(xhi, xlo, wihi, wilo, b_in,
                                                  qhi, qlo, khi, klo, v);
  vt_make<<<BH, 256, 0, stream>>>(v, vthi, vtlo);
  attn_mfma<<<dim3(4, BH), 256, 0, stream>>>(qhi, qlo, khi, klo, depth, rpe, lscale, Pout);
  attn_row256<<<BH, 256, 0, stream>>>(qhi, qlo, khi, klo, depth, rpe, lscale, Pout);
  pv_mfma<<<dim3(2, BH), 256, 0, stream>>>(Pout, vthi, vtlo, v, ahi, alo);

  gemm_out<<<MT_Q * NT_O, 256, 0, stream>>>(ahi, alo, wohi, wolo, b_out, out);
}

// Round 5
// 445.924 us; speedup vs baseline: 1.3196x; 1.0188x over previous
//
#include <hip/hip_runtime.h>
#include <math.h>

#define L_TOK 257
#define N_B 32
#define C_DIM 768
#define N_H 12
#define HD 64
#define BH (N_B * N_H)          /* 384 */
#define M_TOK (L_TOK * N_B)     /* 8224 */
#define HW 256
#define RPE_NUM 33
#define LOGIT_MAX 4.6051701859880913680f
#define VT_STRIDE 264
#define MT_Q 65                 /* gemm M-tiles (128-row) */
#define NT_Q 18                 /* QKV gemm N-tiles (128-col) */
#define NT_O 6                  /* out-proj N-tiles (128-col) */
#define NTK 24                  /* K-steps (768/32) */

typedef unsigned short ushort;
typedef unsigned int uint;
typedef __attribute__((ext_vector_type(8))) short short8;
typedef __attribute__((ext_vector_type(4))) float f32x4;

__device__ __forceinline__ ushort f2bf_rn(float f) {
  uint u = __float_as_uint(f);
  uint r = (u + 0x7FFF + ((u >> 16) & 1)) >> 16;
  return (ushort)r;
}
__device__ __forceinline__ float bf2f(ushort h) {
  return __uint_as_float(((uint)h) << 16);
}

__device__ __forceinline__ int xcd_swz(int wid, int nwg) {
  int q = nwg >> 3, r = nwg & 7;
  int xcd = wid & 7, pos = wid >> 3;
  int base = (xcd < r) ? xcd * (q + 1) : r * (q + 1) + (xcd - r) * q;
  return base + pos;
}

// 2-D supertile map: contiguous wid-chunks cover 8-m-tile x NT-n-tile rects.
__device__ __forceinline__ void tile_map(int bid, int MT, int NT, int nwg,
                                         int& m0, int& nt) {
  int wid = xcd_swz(bid, nwg);
  int per = 8 * NT;
  int s = wid / per;
  int rem = wid - s * per;
  int msz = MT - s * 8; if (msz > 8) msz = 8;
  int mi = rem % msz, ni = rem / msz;
  m0 = (s * 8 + mi) * 128;
  nt = ni;
}

// ---------------- fp32 -> bf16 hi/lo split ----------------
__global__ __launch_bounds__(256)
void cvt_split(const float* __restrict__ src, ushort* __restrict__ hi,
               ushort* __restrict__ lo, int n) {
  int i = (blockIdx.x * 256 + threadIdx.x) * 4;
  if (i + 3 >= n + 3) return;
  if (i + 3 < n) {
    float4 v = *(const float4*)(src + i);
    ushort h0 = f2bf_rn(v.x), h1 = f2bf_rn(v.y), h2 = f2bf_rn(v.z), h3 = f2bf_rn(v.w);
    ushort l0 = f2bf_rn(v.x - bf2f(h0)), l1 = f2bf_rn(v.y - bf2f(h1));
    ushort l2 = f2bf_rn(v.z - bf2f(h2)), l3 = f2bf_rn(v.w - bf2f(h3));
    *(ushort4*)(hi + i) = make_ushort4(h0, h1, h2, h3);
    *(ushort4*)(lo + i) = make_ushort4(l0, l1, l2, l3);
  } else {
    for (int k = i; k < n; ++k) {
      float vv = src[k];
      ushort h = f2bf_rn(vv);
      hi[k] = h; lo[k] = f2bf_rn(vv - bf2f(h));
    }
  }
}

// ---------------- counted-vmcnt 2-phase split-3 GEMM core ----------------
// BM=BN=128, BK=32, 4 waves, dbuf LDS 64KB. Phases per K-step:
//   P1: vmcnt(4){own AhBh} -> barrier -> ds ah,bh -> issue next AhBh -> 16 mfma hh
//   P2: vmcnt(4){own AlBl} -> barrier -> ds al,bl -> issue next AlBl -> 32 mfma lh+hl
// vmcnt never drains to 0 in the main loop; 8 loads stay in flight.
// T2 swizzle: LDS dest linear (global_load_lds), global SOURCE col pre-swizzled
// by slot^((row>>1)&3); fragment reads apply the same XOR (involution).
__device__ __forceinline__ void stage_pair(const ushort* g0, const ushort* g1,
                                           ushort* l, uint so) {
  __builtin_amdgcn_global_load_lds(
      (const __attribute__((address_space(1))) void*)g0,
      (__attribute__((address_space(3))) void*)((char*)l + so), 16, 0, 0);
  __builtin_amdgcn_global_load_lds(
      (const __attribute__((address_space(1))) void*)g1,
      (__attribute__((address_space(3))) void*)((char*)l + so + 4096), 16, 0, 0);
}

#define PH_WAIT(N)                                        \
  asm volatile("s_waitcnt vmcnt(" #N ")" ::: "memory");   \
  __builtin_amdgcn_s_barrier();                           \
  __builtin_amdgcn_sched_barrier(0);

#define PH_LGKM()                                         \
  asm volatile("s_waitcnt lgkmcnt(0)" ::: "memory");      \
  __builtin_amdgcn_sched_barrier(0);

__device__ __forceinline__ void gemm3_core(
    const ushort* __restrict__ Ahi, const ushort* __restrict__ Alo,
    const ushort* __restrict__ Bhi, const ushort* __restrict__ Blo,
    int m0, int n0, ushort* lds, f32x4 (&acc)[4][4]) {
  const int K = C_DIM, M = M_TOK;
  const int t = threadIdx.x;
  const int wave = t >> 6, lane = t & 63;
  const int wm = (wave & 1) * 64, wn = (wave >> 1) * 64;
  const int frm = lane & 15, fs = lane >> 4;
  const int sx = (fs ^ ((frm >> 1) & 3)) * 8;   // read-side swizzled slot

  const int ar = t >> 2;
  const int acs = ((t & 3) ^ ((ar >> 1) & 3)) * 8;
  const uint so = (uint)(t & 192) * 16;         // wave-uniform byte base

  int rA0 = m0 + ar;      if (rA0 > M - 1) rA0 = M - 1;
  int rA1 = m0 + 64 + ar; if (rA1 > M - 1) rA1 = M - 1;
  const size_t gA0 = (size_t)rA0 * K + acs;
  const size_t gA1 = (size_t)rA1 * K + acs;
  const size_t gB0 = (size_t)(n0 + ar) * K + acs;
  const size_t gB1 = (size_t)(n0 + 64 + ar) * K + acs;

  // prologue: tile 0 -> buf 0, issue order AhBh (4) then AlBl (4)
  stage_pair(Ahi + gA0, Ahi + gA1, lds, so);
  stage_pair(Bhi + gB0, Bhi + gB1, lds + 4096, so);
  stage_pair(Alo + gA0, Alo + gA1, lds + 8192, so);
  stage_pair(Blo + gB0, Blo + gB1, lds + 12288, so);

  short8 ah[4], bh[4], al[4], bl[4];

#pragma unroll 2
  for (int kt = 0; kt < NTK - 1; ++kt) {
    const int curo = (kt & 1) << 14;
    const int nxo = curo ^ 16384;
    const int kn = (kt + 1) * 32;
    // ---- P1: hh ----
    PH_WAIT(4)
#pragma unroll
    for (int i = 0; i < 4; ++i) {
      ah[i] = *(const short8*)(lds + curo + (wm + i * 16 + frm) * 32 + sx);
      bh[i] = *(const short8*)(lds + curo + 4096 + (wn + i * 16 + frm) * 32 + sx);
    }
    stage_pair(Ahi + gA0 + kn, Ahi + gA1 + kn, lds + nxo, so);
    stage_pair(Bhi + gB0 + kn, Bhi + gB1 + kn, lds + nxo + 4096, so);
    PH_LGKM()
    __builtin_amdgcn_s_setprio(1);
#pragma unroll
    for (int i = 0; i < 4; ++i)
#pragma unroll
      for (int j = 0; j < 4; ++j)
        acc[i][j] = __builtin_amdgcn_mfma_f32_16x16x32_bf16(ah[i], bh[j], acc[i][j], 0, 0, 0);
    __builtin_amdgcn_s_setprio(0);
    __builtin_amdgcn_sched_barrier(0);
    // ---- P2: lh + hl ----
    PH_WAIT(4)
#pragma unroll
    for (int i = 0; i < 4; ++i) {
      al[i] = *(const short8*)(lds + curo + 8192 + (wm + i * 16 + frm) * 32 + sx);
      bl[i] = *(const short8*)(lds + curo + 12288 + (wn + i * 16 + frm) * 32 + sx);
    }
    stage_pair(Alo + gA0 + kn, Alo + gA1 + kn, lds + nxo + 8192, so);
    stage_pair(Blo + gB0 + kn, Blo + gB1 + kn, lds + nxo + 12288, so);
    PH_LGKM()
    __builtin_amdgcn_s_setprio(1);
#pragma unroll
    for (int i = 0; i < 4; ++i)
#pragma unroll
      for (int j = 0; j < 4; ++j)
        acc[i][j] = __builtin_amdgcn_mfma_f32_16x16x32_bf16(al[i], bh[j], acc[i][j], 0, 0, 0);
#pragma unroll
    for (int i = 0; i < 4; ++i)
#pragma unroll
      for (int j = 0; j < 4; ++j)
        acc[i][j] = __builtin_amdgcn_mfma_f32_16x16x32_bf16(ah[i], bl[j], acc[i][j], 0, 0, 0);
    __builtin_amdgcn_s_setprio(0);
    __builtin_amdgcn_sched_barrier(0);
  }
  // ---- final K-step: no issues, drain counts 4/0 ----
  {
    const int curo = ((NTK - 1) & 1) << 14;
    PH_WAIT(4)
#pragma unroll
    for (int i = 0; i < 4; ++i) {
      ah[i] = *(const short8*)(lds + curo + (wm + i * 16 + frm) * 32 + sx);
      bh[i] = *(const short8*)(lds + curo + 4096 + (wn + i * 16 + frm) * 32 + sx);
    }
    PH_LGKM()
#pragma unroll
    for (int i = 0; i < 4; ++i)
#pragma unroll
      for (int j = 0; j < 4; ++j)
        acc[i][j] = __builtin_amdgcn_mfma_f32_16x16x32_bf16(ah[i], bh[j], acc[i][j], 0, 0, 0);
    __builtin_amdgcn_sched_barrier(0);
    PH_WAIT(0)
#pragma unroll
    for (int i = 0; i < 4; ++i) {
      al[i] = *(const short8*)(lds + curo + 8192 + (wm + i * 16 + frm) * 32 + sx);
      bl[i] = *(const short8*)(lds + curo + 12288 + (wn + i * 16 + frm) * 32 + sx);
    }
    PH_LGKM()
#pragma unroll
    for (int i = 0; i < 4; ++i)
#pragma unroll
      for (int j = 0; j < 4; ++j)
        acc[i][j] = __builtin_amdgcn_mfma_f32_16x16x32_bf16(al[i], bh[j], acc[i][j], 0, 0, 0);
#pragma unroll
    for (int i = 0; i < 4; ++i)
#pragma unroll
      for (int j = 0; j < 4; ++j)
        acc[i][j] = __builtin_amdgcn_mfma_f32_16x16x32_bf16(ah[i], bl[j], acc[i][j], 0, 0, 0);
    __builtin_amdgcn_sched_barrier(0);
  }
}

// ---------------- fused QKV GEMM (2-phase core + norm epilogue) ----------------
__global__ __launch_bounds__(256, 2)
void gemm_qkv_fused(const ushort* __restrict__ Ahi, const ushort* __restrict__ Alo,
                    const ushort* __restrict__ Bhi, const ushort* __restrict__ Blo,
                    const float* __restrict__ bias,
                    ushort* __restrict__ qhi, ushort* __restrict__ qlo,
                    ushort* __restrict__ khi, ushort* __restrict__ klo,
                    float* __restrict__ vout) {
  __shared__ __align__(16) ushort lds[32768];   // 64 KB dbuf
  int m0, nt;
  tile_map(blockIdx.x, MT_Q, NT_Q, MT_Q * NT_Q, m0, nt);
  const int n0 = nt * 128;
  f32x4 acc[4][4] = {};
  gemm3_core(Ahi, Alo, Bhi, Blo, m0, n0, lds, acc);

  const int M = M_TOK;
  const int t = threadIdx.x;
  const int wave = t >> 6, lane = t & 63;
  const int wm = (wave & 1) * 64, wn = (wave >> 1) * 64;
  const int c0 = lane & 15, g = lane >> 4;
  const int colBase = n0 + wn;                 // multiple of 64 -> one head
  const int sect = colBase / C_DIM;            // 0:q 1:k 2:v
  const int hh = (colBase - sect * C_DIM) >> 6;
  float bv[4];
#pragma unroll
  for (int j = 0; j < 4; ++j) bv[j] = bias[colBase + j * 16 + c0];

#pragma unroll
  for (int i = 0; i < 4; ++i) {
#pragma unroll
    for (int r = 0; r < 4; ++r) {
      const int row = m0 + wm + i * 16 + g * 4 + r;
      float lv[4];
#pragma unroll
      for (int j = 0; j < 4; ++j) lv[j] = acc[i][j][r] + bv[j];
      if (sect == 2) {
        if (row < M) {
          int l = row >> 5, n = row & 31;
          size_t ob = ((size_t)((n * N_H + hh) * L_TOK + l)) * HD;
#pragma unroll
          for (int j = 0; j < 4; ++j) vout[ob + j * 16 + c0] = lv[j];
        }
      } else {
        float ss = lv[0] * lv[0] + lv[1] * lv[1] + lv[2] * lv[2] + lv[3] * lv[3];
        ss += __shfl_xor(ss, 1);
        ss += __shfl_xor(ss, 2);
        ss += __shfl_xor(ss, 4);
        ss += __shfl_xor(ss, 8);
        float inv = 1.0f / fmaxf(sqrtf(ss), 1e-12f);
        if (row < M) {
          int l = row >> 5, n = row & 31;
          size_t ob = ((size_t)((n * N_H + hh) * L_TOK + l)) * HD;
          ushort* dh = sect ? khi : qhi;
          ushort* dl = sect ? klo : qlo;
#pragma unroll
          for (int j = 0; j < 4; ++j) {
            float val = lv[j] * inv;
            ushort hv = f2bf_rn(val);
            dh[ob + j * 16 + c0] = hv;
            dl[ob + j * 16 + c0] = f2bf_rn(val - bf2f(hv));
          }
        }
      }
    }
  }
}

// ---------------- out-proj GEMM (2-phase core + bias epilogue) ----------------
__global__ __launch_bounds__(256, 2)
void gemm_out(const ushort* __restrict__ Ahi, const ushort* __restrict__ Alo,
              const ushort* __restrict__ Bhi, const ushort* __restrict__ Blo,
              const float* __restrict__ bias, float* __restrict__ Cout) {
  __shared__ __align__(16) ushort lds[32768];
  int m0, nt;
  tile_map(blockIdx.x, MT_Q, NT_O, MT_Q * NT_O, m0, nt);
  const int n0 = nt * 128;
  f32x4 acc[4][4] = {};
  gemm3_core(Ahi, Alo, Bhi, Blo, m0, n0, lds, acc);

  const int M = M_TOK, Nn = C_DIM;
  const int t = threadIdx.x;
  const int wave = t >> 6, lane = t & 63;
  const int wm = (wave & 1) * 64, wn = (wave >> 1) * 64;
  const int ecol = lane & 15;
#pragma unroll
  for (int j = 0; j < 4; ++j) {
    int col = n0 + wn + j * 16 + ecol;
    float bv = bias[col];
#pragma unroll
    for (int i = 0; i < 4; ++i) {
      int rbase = m0 + wm + i * 16 + (lane >> 4) * 4;
#pragma unroll
      for (int r = 0; r < 4; ++r) {
        int row = rbase + r;
        if (row < M) Cout[(size_t)row * Nn + col] = acc[i][j][r] + bv;
      }
    }
  }
}

// ---------------- V transpose ----------------
__global__ __launch_bounds__(256)
void vt_make(const float* __restrict__ v, ushort* __restrict__ vthi,
             ushort* __restrict__ vtlo) {
  __shared__ float sT[64][65];
  const int b = blockIdx.x;
  const int t = threadIdx.x;
  const float* vb = v + (size_t)b * L_TOK * HD;
  ushort* vh = vthi + (size_t)b * HD * VT_STRIDE;
  ushort* vl = vtlo + (size_t)b * HD * VT_STRIDE;
  for (int k0 = 0; k0 < 256; k0 += 64) {
#pragma unroll
    for (int p = 0; p < 16; ++p) {
      int idx = p * 256 + t;
      int k = idx >> 6, d = idx & 63;
      sT[d][k] = vb[(size_t)(k0 + k) * HD + d];
    }
    __syncthreads();
#pragma unroll
    for (int p = 0; p < 16; ++p) {
      int idx = p * 256 + t;
      int d = idx >> 6, k = idx & 63;
      float val = sT[d][k];
      ushort h = f2bf_rn(val);
      vh[(size_t)d * VT_STRIDE + k0 + k] = h;
      vl[(size_t)d * VT_STRIDE + k0 + k] = f2bf_rn(val - bf2f(h));
    }
    __syncthreads();
  }
  if (t < HD) {
    float val = vb[(size_t)256 * HD + t];
    ushort h = f2bf_rn(val);
    vh[(size_t)t * VT_STRIDE + 256] = h;
    vl[(size_t)t * VT_STRIDE + 256] = f2bf_rn(val - bf2f(h));
  }
}

// ---------------- MFMA attention: rows 0..255 (+ row 256 in tile 0), softmax -> P ----------------
__global__ __launch_bounds__(256)
void attn_mfma(const ushort* __restrict__ qhi, const ushort* __restrict__ qlo,
               const ushort* __restrict__ khi, const ushort* __restrict__ klo,
               const float* __restrict__ depth, const float* __restrict__ rpe,
               const float* __restrict__ lscale, float* __restrict__ P) {
  __shared__ __align__(16) ushort sKh[256 * 72];
  __shared__ __align__(16) ushort sKl[256 * 72];
  __shared__ float cz_s[HW];
  __shared__ float txd[32], tyd[32], tzt[36];
  __shared__ float red_s[16];
  __shared__ float s256[4][16];
  __shared__ float qs[HD];
  __shared__ float lg6_sh;

  const int tile = blockIdx.x;
  const int b = blockIdx.y;
  const int n = b / N_H, h = b - n * N_H;
  const int t = threadIdx.x;
  const int lane = t & 63, wave = t >> 6;

  float dval = depth[n * HW + t];
  float mn = dval, mx = dval;
#pragma unroll
  for (int o = 32; o > 0; o >>= 1) {
    mn = fminf(mn, __shfl_down(mn, o));
    mx = fmaxf(mx, __shfl_down(mx, o));
  }
  if (lane == 0) { red_s[wave] = mn; red_s[8 + wave] = mx; }
  __syncthreads();
  float zmin = fminf(fminf(red_s[0], red_s[1]), fminf(red_s[2], red_s[3]));
  float zmax = fmaxf(fmaxf(red_s[8], red_s[9]), fmaxf(red_s[10], red_s[11]));
  float den = zmax - zmin + 1e-8f;
  cz_s[t] = (dval - zmin) / den;
  if (t < 31) {
    int d = t - 15;
    int ix = (int)rintf((float)d * (16.0f / 15.0f));
    ix = max(-16, min(16, ix));
    txd[t] = rpe[(ix + 16) * N_H + h];
    tyd[t] = rpe[(RPE_NUM + ix + 16) * N_H + h];
  }
  if (t < RPE_NUM) tzt[t] = rpe[(2 * RPE_NUM + t) * N_H + h];
  const float scale = expf(fminf(lscale[h], LOGIT_MAX));

  const ushort* khb = khi + (size_t)b * L_TOK * HD;
  const ushort* klb = klo + (size_t)b * L_TOK * HD;
#pragma unroll
  for (int it = 0; it < 8; ++it) {
    int idx = it * 256 + t;
    int j = idx >> 3, c = (idx & 7) * 8;
    *(uint4*)(sKh + j * 72 + c) = *(const uint4*)(khb + (size_t)j * HD + c);
    *(uint4*)(sKl + j * 72 + c) = *(const uint4*)(klb + (size_t)j * HD + c);
  }
  __syncthreads();

  const int qrow = tile * 64 + 16 * wave;
  const size_t qoff = ((size_t)b * L_TOK + qrow + (lane & 15)) * HD + (lane >> 4) * 8;
  short8 qh0 = *(const short8*)(qhi + qoff);
  short8 qh1 = *(const short8*)(qhi + qoff + 32);
  short8 ql0 = *(const short8*)(qlo + qoff);
  short8 ql1 = *(const short8*)(qlo + qoff + 32);

  f32x4 acc[16] = {};
#pragma unroll
  for (int jt = 0; jt < 16; ++jt) {
    const ushort* bp = sKh + (jt * 16 + (lane & 15)) * 72 + (lane >> 4) * 8;
    const ushort* bq = sKl + (jt * 16 + (lane & 15)) * 72 + (lane >> 4) * 8;
    short8 bh0 = *(const short8*)(bp);
    short8 bh1 = *(const short8*)(bp + 32);
    short8 bl0 = *(const short8*)(bq);
    short8 bl1 = *(const short8*)(bq + 32);
    acc[jt] = __builtin_amdgcn_mfma_f32_16x16x32_bf16(qh0, bh0, acc[jt], 0, 0, 0);
    acc[jt] = __builtin_amdgcn_mfma_f32_16x16x32_bf16(qh1, bh1, acc[jt], 0, 0, 0);
    acc[jt] = __builtin_amdgcn_mfma_f32_16x16x32_bf16(qh0, bl0, acc[jt], 0, 0, 0);
    acc[jt] = __builtin_amdgcn_mfma_f32_16x16x32_bf16(qh1, bl1, acc[jt], 0, 0, 0);
    acc[jt] = __builtin_amdgcn_mfma_f32_16x16x32_bf16(ql0, bh0, acc[jt], 0, 0, 0);
    acc[jt] = __builtin_amdgcn_mfma_f32_16x16x32_bf16(ql1, bh1, acc[jt], 0, 0, 0);
  }

  {
    const ushort* k6h = khb + (size_t)256 * HD + (lane >> 4) * 8;
    const ushort* k6l = klb + (size_t)256 * HD + (lane >> 4) * 8;
    float p = 0.f;
#pragma unroll
    for (int j = 0; j < 8; ++j) {
      float kf0 = bf2f(k6h[j]) + bf2f(k6l[j]);
      float kf1 = bf2f(k6h[32 + j]) + bf2f(k6l[32 + j]);
      float qf0 = bf2f((ushort)qh0[j]) + bf2f((ushort)ql0[j]);
      float qf1 = bf2f((ushort)qh1[j]) + bf2f((ushort)ql1[j]);
      p = fmaf(qf0, kf0, fmaf(qf1, kf1, p));
    }
    p += __shfl_xor(p, 16);
    p += __shfl_xor(p, 32);
    if (lane < 16) s256[wave][lane] = p;
  }

  const int g = lane >> 4, c0 = lane & 15;

  float lg6[4];
#pragma unroll
  for (int r = 0; r < 4; ++r) {
    int gi = tile * 64 + 16 * wave + 4 * g + r;
    float d6 = s256[wave][4 * g + r];
    float bz = 0.f;
    if (gi >= 1) {
      int dx = ((gi - 1) & 15) - 15;
      int dy = ((gi - 1) >> 4) - 15;
      float rz = (cz_s[gi - 1] - cz_s[255]) * 16.0f;
      int iz = (int)rintf(rz); iz = max(-16, min(16, iz));
      bz = txd[dx + 15] + tyd[dy + 15] + tzt[iz + 16];
    }
    lg6[r] = scale * d6 + bz;
  }

#pragma unroll
  for (int jt = 0; jt < 16; ++jt) {
    int col = jt * 16 + c0;
#pragma unroll
    for (int r = 0; r < 4; ++r) {
      int gi = tile * 64 + 16 * wave + 4 * g + r;
      float lv = scale * acc[jt][r];
      if (col >= 1 && gi >= 1) {
        int dx = ((gi - 1) & 15) - ((col - 1) & 15);
        int dy = ((gi - 1) >> 4) - ((col - 1) >> 4);
        float rz = (cz_s[gi - 1] - cz_s[col - 1]) * 16.0f;
        int iz = (int)rintf(rz); iz = max(-16, min(16, iz));
        lv += txd[dx + 15] + tyd[dy + 15] + tzt[iz + 16];
      }
      acc[jt][r] = lv;
    }
  }

  float* Pb_ = P + (size_t)b * L_TOK * L_TOK;
#pragma unroll
  for (int r = 0; r < 4; ++r) {
    int gi = tile * 64 + 16 * wave + 4 * g + r;
    float m = acc[0][r];
#pragma unroll
    for (int jt = 1; jt < 16; ++jt) m = fmaxf(m, acc[jt][r]);
#pragma unroll
    for (int o = 1; o < 16; o <<= 1) m = fmaxf(m, __shfl_xor(m, o));
    m = fmaxf(m, lg6[r]);
    float s = 0.f;
#pragma unroll
    for (int jt = 0; jt < 16; ++jt) {
      float e = __expf(acc[jt][r] - m);
      acc[jt][r] = e;
      s += e;
    }
#pragma unroll
    for (int o = 1; o < 16; o <<= 1) s += __shfl_xor(s, o);
    float e6 = __expf(lg6[r] - m);
    float inv = 1.0f / (s + e6);
    float* Prow = Pb_ + (size_t)gi * L_TOK;
#pragma unroll
    for (int jt = 0; jt < 16; ++jt)
      Prow[jt * 16 + c0] = acc[jt][r] * inv;
    if (c0 == 0) Prow[256] = e6 * inv;
  }

  // ---- fused row 256 (tile 0 only): K rows read from LDS staging ----
  if (tile == 0) {
    __syncthreads();
    const size_t q6 = ((size_t)b * L_TOK + 256) * HD;
    if (t < HD) qs[t] = bf2f(qhi[q6 + t]) + bf2f(qlo[q6 + t]);
    __syncthreads();

    const ushort* krh = sKh + t * 72;
    const ushort* krl = sKl + t * 72;
    float dot = 0.f;
#pragma unroll
    for (int c = 0; c < HD; c += 8) {
      ushort4 hv0 = *(const ushort4*)(krh + c);
      ushort4 hv1 = *(const ushort4*)(krh + c + 4);
      ushort4 lv0 = *(const ushort4*)(krl + c);
      ushort4 lv1 = *(const ushort4*)(krl + c + 4);
      dot = fmaf(bf2f(hv0.x) + bf2f(lv0.x), qs[c + 0], dot);
      dot = fmaf(bf2f(hv0.y) + bf2f(lv0.y), qs[c + 1], dot);
      dot = fmaf(bf2f(hv0.z) + bf2f(lv0.z), qs[c + 2], dot);
      dot = fmaf(bf2f(hv0.w) + bf2f(lv0.w), qs[c + 3], dot);
      dot = fmaf(bf2f(hv1.x) + bf2f(lv1.x), qs[c + 4], dot);
      dot = fmaf(bf2f(hv1.y) + bf2f(lv1.y), qs[c + 5], dot);
      dot = fmaf(bf2f(hv1.z) + bf2f(lv1.z), qs[c + 6], dot);
      dot = fmaf(bf2f(hv1.w) + bf2f(lv1.w), qs[c + 7], dot);
    }

    float lg;
    {
      float bsum = 0.f;
      if (t >= 1) {
        int dx = 15 - ((t - 1) & 15);
        int dy = 15 - ((t - 1) >> 4);
        float rz = (cz_s[255] - cz_s[t - 1]) * 16.0f;
        int iz = (int)rintf(rz); iz = max(-16, min(16, iz));
        bsum = txd[dx + 15] + tyd[dy + 15] + tzt[iz + 16];
      }
      lg = scale * dot + bsum;
    }

    if (wave == 0) {
      const ushort* k6h = khi + q6;
      const ushort* k6l = klo + q6;
      float pp = (bf2f(k6h[lane]) + bf2f(k6l[lane])) * qs[lane];
#pragma unroll
      for (int o = 32; o > 0; o >>= 1) pp += __shfl_down(pp, o);
      if (lane == 0) {
        float bz = txd[15] + tyd[15] + tzt[16];
        lg6_sh = scale * pp + bz;
      }
    }

    float m = lg;
#pragma unroll
    for (int o = 32; o > 0; o >>= 1) m = fmaxf(m, __shfl_down(m, o));
    if (lane == 0) red_s[wave] = m;
    __syncthreads();
    float M = fmaxf(fmaxf(red_s[0], red_s[1]), fmaxf(red_s[2], red_s[3]));
    M = fmaxf(M, lg6_sh);
    float e = __expf(lg - M);
    float s = e;
#pragma unroll
    for (int o = 32; o > 0; o >>= 1) s += __shfl_down(s, o);
    if (lane == 0) red_s[8 + wave] = s;
    __syncthreads();
    float e6 = __expf(lg6_sh - M);
    float S = (red_s[8] + red_s[9]) + (red_s[10] + red_s[11]) + e6;
    float inv = 1.0f / S;
    float* Prow = Pb_ + (size_t)256 * L_TOK;
    Prow[t] = e * inv;
    if (t == 0) Prow[256] = e6 * inv;
  }
}

// ---------------- PV via MFMA -> bf16 hi/lo A for out-proj ----------------
__global__ __launch_bounds__(256)
void pv_mfma(const float* __restrict__ P, const ushort* __restrict__ vthi,
             const ushort* __restrict__ vtlo, const float* __restrict__ v,
             ushort* __restrict__ ahi, ushort* __restrict__ alo) {
  const int b = blockIdx.y;
  const int n = b / N_H, h = b - n * N_H;
  const int t = threadIdx.x;
  const int lane = t & 63, wave = t >> 6;
  const int rbase = blockIdx.x * 128 + wave * 32;
  const float* Pb = P + (size_t)b * L_TOK * L_TOK;
  const ushort* vh = vthi + (size_t)b * HD * VT_STRIDE;
  const ushort* vl = vtlo + (size_t)b * HD * VT_STRIDE;

  const int fm = lane & 15, fk = (lane >> 4) * 8;
  f32x4 acc[2][4] = {};

  for (int k0 = 0; k0 < 256; k0 += 32) {
    short8 ah[2], al[2], bh[4], bl[4];
#pragma unroll
    for (int i = 0; i < 2; ++i) {
      const float* pr = Pb + (size_t)(rbase + i * 16 + fm) * L_TOK + k0 + fk;
#pragma unroll
      for (int j = 0; j < 8; ++j) {
        float pv_ = pr[j];
        ushort hh = f2bf_rn(pv_);
        ah[i][j] = (short)hh;
        al[i][j] = (short)f2bf_rn(pv_ - bf2f(hh));
      }
    }
#pragma unroll
    for (int j = 0; j < 4; ++j) {
      const ushort* bp = vh + (size_t)(j * 16 + fm) * VT_STRIDE + k0 + fk;
      const ushort* bq = vl + (size_t)(j * 16 + fm) * VT_STRIDE + k0 + fk;
      bh[j] = *(const short8*)bp;
      bl[j] = *(const short8*)bq;
    }
#pragma unroll
    for (int i = 0; i < 2; ++i)
#pragma unroll
      for (int j = 0; j < 4; ++j) {
        acc[i][j] = __builtin_amdgcn_mfma_f32_16x16x32_bf16(ah[i], bh[j], acc[i][j], 0, 0, 0);
        acc[i][j] = __builtin_amdgcn_mfma_f32_16x16x32_bf16(ah[i], bl[j], acc[i][j], 0, 0, 0);
        acc[i][j] = __builtin_amdgcn_mfma_f32_16x16x32_bf16(al[i], bh[j], acc[i][j], 0, 0, 0);
        acc[i][j] = __builtin_amdgcn_mfma_f32_16x16x32_bf16(al[i], bl[j], acc[i][j], 0, 0, 0);
      }
  }

  const int g = lane >> 4;
  float v6[4];
#pragma unroll
  for (int j = 0; j < 4; ++j)
    v6[j] = v[((size_t)b * L_TOK + 256) * HD + j * 16 + fm];
#pragma unroll
  for (int i = 0; i < 2; ++i)
#pragma unroll
    for (int r = 0; r < 4; ++r) {
      int row = rbase + i * 16 + g * 4 + r;
      float p6 = Pb[(size_t)row * L_TOK + 256];
#pragma unroll
      for (int j = 0; j < 4; ++j) acc[i][j][r] += p6 * v6[j];
    }

#pragma unroll
  for (int i = 0; i < 2; ++i)
#pragma unroll
    for (int r = 0; r < 4; ++r) {
      int row = rbase + i * 16 + g * 4 + r;
      size_t o = ((size_t)row * N_B + n) * C_DIM + h * HD;
#pragma unroll
      for (int j = 0; j < 4; ++j) {
        float val = acc[i][j][r];
        ushort hv = f2bf_rn(val);
        ahi[o + j * 16 + fm] = hv;
        alo[o + j * 16 + fm] = f2bf_rn(val - bf2f(hv));
      }
    }

  if (blockIdx.x == 0 && t < HD) {
    const float* Prow = Pb + (size_t)256 * L_TOK;
    const float* vb = v + (size_t)b * L_TOK * HD;
    float sum = 0.f;
    for (int k = 0; k < L_TOK; ++k)
      sum = fmaf(Prow[k], vb[(size_t)k * HD + t], sum);
    size_t o = ((size_t)256 * N_B + n) * C_DIM + h * HD + t;
    ushort hv = f2bf_rn(sum);
    ahi[o] = hv;
    alo[o] = f2bf_rn(sum - bf2f(hv));
  }
}

extern "C" void kernel_launch(void* const* d_in, const int* in_sizes, int n_in,
                              void* d_out, int out_size, void* d_ws, size_t ws_size,
                              hipStream_t stream) {
  const float* x      = (const float*)d_in[0];
  const float* depth  = (const float*)d_in[1];
  const float* w_in   = (const float*)d_in[2];
  const float* b_in   = (const float*)d_in[3];
  const float* w_out  = (const float*)d_in[4];
  const float* b_out  = (const float*)d_in[5];
  const float* rpe    = (const float*)d_in[6];
  const float* lscale = (const float*)d_in[7];
  float* out = (float*)d_out;
  float* ws = (float*)d_ws;

  ushort* xhi  = (ushort*)ws;                   // 6,316,032 ushorts
  ushort* xlo  = xhi + 6316032;
  ushort* vthi = (ushort*)(ws + 6316032);       // 6,488,064 ushorts each
  ushort* vtlo = vthi + 6488064;
  float*  v    = ws + 18948096;                 // 6,316,032 floats
  ushort* qhi  = (ushort*)(ws + 25264128);      // 6,316,032 ushorts each
  ushort* qlo  = qhi + 6316032;
  ushort* khi  = qlo + 6316032;
  ushort* klo  = khi + 6316032;
  ushort* wihi = (ushort*)(ws + 37896192);      // 1,769,472 each
  ushort* wilo = wihi + 1769472;
  ushort* wohi = wilo + 1769472;                // 589,824 each
  ushort* wolo = wohi + 589824;
  ushort* ahi  = xhi;                           // overlay: x splits dead after QKV gemm
  ushort* alo  = xlo;
  float* Pout = out + 6316032;

  cvt_split<<<6168, 256, 0, stream>>>(x, xhi, xlo, 6316032);
  cvt_split<<<1728, 256, 0, stream>>>(w_in, wihi, wilo, 1769472);
  cvt_split<<<576, 256, 0, stream>>>(w_out, wohi, wolo, 589824);

  gemm_qkv_fused<<<MT_Q * NT_Q, 256, 0, stream>>>(xhi, xlo, wihi, wilo, b_in,
                                                  qhi, qlo, khi, klo, v);
  vt_make<<<BH, 256, 0, stream>>>(v, vthi, vtlo);
  attn_mfma<<<dim3(4, BH), 256, 0, stream>>>(qhi, qlo, khi, klo, depth, rpe, lscale, Pout);
  pv_mfma<<<dim3(2, BH), 256, 0, stream>>>(Pout, vthi, vtlo, v, ahi, alo);

  gemm_out<<<MT_Q * NT_O, 256, 0, stream>>>(ahi, alo, wohi, wolo, b_out, out);
}